// Round 14
// baseline (233.143 us; speedup 1.0000x reference)
//
#include <hip/hip_runtime.h>
#include <hip/hip_fp16.h>
#include <math.h>

#define NN 50000
#define EE 800000
#define NB 196  // ceil(NN/256)
// IN_DIM = 128, HEADS*HIDDEN = 128, NUM_CLASSES = 10

typedef _Float16 f16x8 __attribute__((ext_vector_type(8)));
typedef float f32x4 __attribute__((ext_vector_type(4)));

__device__ inline float elu1(float x) { return x > 0.f ? x : expm1f(x); }

// ---------- prep: W1 transpose (f16) + W2 pack (f16, zero-padded) in one kernel ----------
__global__ __launch_bounds__(256) void build_weights(
    const float* __restrict__ Wq, const float* __restrict__ Wk,
    const float* __restrict__ Wv, const float* __restrict__ Ws,
    const float* __restrict__ Wq2, const float* __restrict__ bq2,
    const float* __restrict__ Wk2, const float* __restrict__ bk2,
    const float* __restrict__ Wv2, const float* __restrict__ bv2,
    const float* __restrict__ Ws2, const float* __restrict__ bs2,
    __half* __restrict__ Wt, __half* __restrict__ W2t, float* __restrict__ bias2)
{
    // part A (blocks 0..31): W2[128][10] x4 -> W2t[64][128] zero-padded + bias2[64]
    const int idx = blockIdx.x * 256 + threadIdx.x;
    if (idx < 8192) {
        const int col = idx >> 7, k = idx & 127;
        const int m = col >> 4, j = col & 15;
        const float* W = m == 0 ? Wq2 : m == 1 ? Wk2 : m == 2 ? Wv2 : Ws2;
        W2t[idx] = (__half)(j < 10 ? W[k * 10 + j] : 0.f);
    }
    if (idx < 64) {
        const int m = idx >> 4, j = idx & 15;
        const float* b = m == 0 ? bq2 : m == 1 ? bk2 : m == 2 ? bv2 : bs2;
        bias2[idx] = j < 10 ? b[j] : 0.f;
    }
    // part B (all 64 blocks): W1[k][c] -> Wt[mat][c][k] f16 via LDS tile transpose
    __shared__ float tile[32][33];
    const int mat = blockIdx.x >> 4;
    const int tid = blockIdx.x & 15;
    const int k0 = (tid >> 2) * 32, c0 = (tid & 3) * 32;
    const float* W = mat == 0 ? Wq : mat == 1 ? Wk : mat == 2 ? Wv : Ws;
    const int r = threadIdx.x >> 5;   // 0..7
    const int c = threadIdx.x & 31;
    for (int rr = r; rr < 32; rr += 8) tile[rr][c] = W[(size_t)(k0 + rr) * 128 + c0 + c];
    __syncthreads();
    for (int rr = r; rr < 32; rr += 8)
        Wt[((size_t)mat * 128 + c0 + rr) * 128 + k0 + c] = (__half)tile[c][rr];
}

// ---------- CSR build: histogram (standalone — fusing into MFMA kernel regressed),
// multi-block scan, scatter ----------
__global__ __launch_bounds__(256) void deg_count(
    const int* __restrict__ dst, int* __restrict__ deg)
{
    const int e = blockIdx.x * 256 + threadIdx.x;
    if (e >= EE) return;
    atomicAdd(&deg[dst[e]], 1);
}

__global__ __launch_bounds__(256) void block_sums(
    const int* __restrict__ deg, int* __restrict__ bsum)
{
    __shared__ int ws[4];
    const int t = threadIdx.x;
    const int idx = blockIdx.x * 256 + t;
    int d = (idx < NN) ? deg[idx] : 0;
    #pragma unroll
    for (int off = 32; off; off >>= 1) d += __shfl_down(d, off, 64);
    if ((t & 63) == 0) ws[t >> 6] = d;
    __syncthreads();
    if (t == 0) bsum[blockIdx.x] = ws[0] + ws[1] + ws[2] + ws[3];
}

__global__ __launch_bounds__(256) void scan_bsums(int* __restrict__ bsum)
{
    __shared__ int s[256];
    const int t = threadIdx.x;
    int v = (t < NB) ? bsum[t] : 0;
    s[t] = v;
    __syncthreads();
    for (int off = 1; off < 256; off <<= 1) {
        int u = (t >= off) ? s[t - off] : 0;
        __syncthreads();
        s[t] += u;
        __syncthreads();
    }
    if (t < NB) bsum[t] = (t == 0) ? 0 : s[t - 1];
}

__global__ __launch_bounds__(256) void write_rowptr(
    const int* __restrict__ deg, const int* __restrict__ bsum,
    int* __restrict__ rowptr, int* __restrict__ cursor)
{
    __shared__ int s[256];
    const int t = threadIdx.x;
    const int idx = blockIdx.x * 256 + t;
    const int d = (idx < NN) ? deg[idx] : 0;
    s[t] = d;
    __syncthreads();
    for (int off = 1; off < 256; off <<= 1) {
        int u = (t >= off) ? s[t - off] : 0;
        __syncthreads();
        s[t] += u;
        __syncthreads();
    }
    const int excl = ((t == 0) ? 0 : s[t - 1]) + bsum[blockIdx.x];
    if (idx < NN) {
        rowptr[idx] = excl;
        cursor[idx] = excl;
    }
    if (idx == NN - 1) rowptr[NN] = excl + d;  // == EE
}

__global__ __launch_bounds__(256) void scatter_edges(
    const int* __restrict__ src, const int* __restrict__ dst,
    int* __restrict__ cursor, int* __restrict__ esrc)
{
    const int e = blockIdx.x * 256 + threadIdx.x;
    if (e >= EE) return;
    const int d = dst[e];
    const int pos = atomicAdd(&cursor[d], 1);
    esrc[pos] = src[e];
}

// ---------- layer-1 projections via MFMA: ONE matrix per block (blockIdx.y) ----------
// 3128 waves (12/CU) for store-latency hiding; x re-reads are L3-absorbed.
// Reads x f32 directly; all-f16 outputs; each 8B output stored as one uint2.
__global__ __launch_bounds__(128) void gemm_l1_mfma(
    const float* __restrict__ x, const __half* __restrict__ Wt,
    const float* __restrict__ bq, const float* __restrict__ bk,
    const float* __restrict__ bv, const float* __restrict__ bs,
    __half* __restrict__ oqh, __half* __restrict__ okh,
    __half* __restrict__ ovh, __half* __restrict__ osh)
{
    const int mat = blockIdx.y;
    const int t = threadIdx.x;
    const int wave = t >> 6;
    const int lane = t & 63;
    const int l = lane & 15;
    const int g = lane >> 4;  // 0..3
    const int wrow0 = blockIdx.x * 128 + wave * 64;
    if (wrow0 >= NN) return;
    const bool full = (wrow0 + 64 <= NN);

    // x fragments (B operand): f32 load + in-register cvt; lane&15 = row-in-tile
    f16x8 xf[4][4];
    #pragma unroll
    for (int rt = 0; rt < 4; ++rt) {
        int arow = wrow0 + rt * 16 + l;
        if (!full && arow >= NN) arow = NN - 1;  // clamp: garbage rows never stored
        #pragma unroll
        for (int kk = 0; kk < 4; ++kk) {
            const float* xp = x + (size_t)arow * 128 + kk * 32 + g * 8;
            const float4 a = *(const float4*)xp;
            const float4 b = *(const float4*)(xp + 4);
            f16x8 f;
            f[0] = (_Float16)a.x; f[1] = (_Float16)a.y;
            f[2] = (_Float16)a.z; f[3] = (_Float16)a.w;
            f[4] = (_Float16)b.x; f[5] = (_Float16)b.y;
            f[6] = (_Float16)b.z; f[7] = (_Float16)b.w;
            xf[rt][kk] = f;
        }
    }

    const float* b = mat == 0 ? bq : mat == 1 ? bk : mat == 2 ? bv : bs;
    __half* o = mat == 0 ? oqh : mat == 1 ? okh : mat == 2 ? ovh : osh;
    const _Float16* wt = (const _Float16*)Wt + (size_t)mat * 128 * 128;

    // W fragments (A operand): lane&15 = col-in-tile; prefetch 1 ct ahead
    f16x8 wf[4], wfn[4];
    #pragma unroll
    for (int kk = 0; kk < 4; ++kk)
        wf[kk] = *(const f16x8*)(wt + (size_t)l * 128 + kk * 32 + g * 8);

    for (int ct = 0; ct < 8; ++ct) {
        if (ct < 7) {
            const int ncol = (ct + 1) * 16 + l;
            #pragma unroll
            for (int kk = 0; kk < 4; ++kk)
                wfn[kk] = *(const f16x8*)(wt + (size_t)ncol * 128 + kk * 32 + g * 8);
        }
        f32x4 acc[4];
        #pragma unroll
        for (int rt = 0; rt < 4; ++rt) acc[rt] = (f32x4){0.f, 0.f, 0.f, 0.f};
        #pragma unroll
        for (int kk = 0; kk < 4; ++kk)
            #pragma unroll
            for (int rt = 0; rt < 4; ++rt)
                acc[rt] = __builtin_amdgcn_mfma_f32_16x16x32_f16(wf[kk], xf[rt][kk], acc[rt], 0, 0, 0);

        const int col0 = ct * 16 + g * 4;
        const float4 bias = *(const float4*)(b + col0);
        #pragma unroll
        for (int rt = 0; rt < 4; ++rt) {
            const int row = wrow0 + rt * 16 + l;
            if (full || row < NN) {
                __half2 h01 = __floats2half2_rn(acc[rt][0] + bias.x, acc[rt][1] + bias.y);
                __half2 h23 = __floats2half2_rn(acc[rt][2] + bias.z, acc[rt][3] + bias.w);
                uint2 u;
                u.x = *(unsigned*)&h01;
                u.y = *(unsigned*)&h23;
                *(uint2*)(o + (size_t)row * 128 + col0) = u;  // one 8B store
            }
        }
        #pragma unroll
        for (int kk = 0; kk < 4; ++kk) wf[kk] = wfn[kk];
    }
}

// ---------- layer-1 fused attention + skip + ELU -> h (fp16) ----------
// static-shift softmax (shift-invariant; logits ~ N(0,1) so exp(lg-4) is safe).
__global__ __launch_bounds__(256) void node_attn1(
    const __half* __restrict__ q1, const __half* __restrict__ k1,
    const __half* __restrict__ v1,
    const int* __restrict__ rowptr, const int* __restrict__ esrc,
    const __half* __restrict__ skiph,  // x @ Ws + bs (f16)
    __half* __restrict__ hb)           // out: h = elu(skip + attn), fp16
{
    const int t = threadIdx.x;
    const int wid = __builtin_amdgcn_readfirstlane(t >> 6);
    const int d = blockIdx.x * 4 + wid;
    if (d >= NN) return;
    const int lane = t & 63;
    const int ch2 = lane << 1;

    const int beg = rowptr[d];
    const int end = rowptr[d + 1];

    float2 qv = __half22float2(*(const __half2*)(q1 + (size_t)d * 128 + ch2));
    qv.x *= 0.17677669529663687f;  // fold 1/sqrt(32) into q
    qv.y *= 0.17677669529663687f;

    float2 accA = make_float2(0.f, 0.f), accB = make_float2(0.f, 0.f);
    float sA = 0.f, sB = 0.f;

    int i = beg;
    int sa = (i < end) ? esrc[i] : 0;
    int sb = (i + 1 < end) ? esrc[i + 1] : 0;
    __half2 kA = *(const __half2*)(k1 + (size_t)sa * 128 + ch2);
    __half2 vA = *(const __half2*)(v1 + (size_t)sa * 128 + ch2);
    __half2 kB = *(const __half2*)(k1 + (size_t)sb * 128 + ch2);
    __half2 vB = *(const __half2*)(v1 + (size_t)sb * 128 + ch2);

    while (i + 1 < end) {
        const int ni = i + 2;
        const int nsa = (ni < end) ? esrc[ni] : 0;
        const int nsb = (ni + 1 < end) ? esrc[ni + 1] : 0;
        const __half2 nkA = *(const __half2*)(k1 + (size_t)nsa * 128 + ch2);
        const __half2 nvA = *(const __half2*)(v1 + (size_t)nsa * 128 + ch2);
        const __half2 nkB = *(const __half2*)(k1 + (size_t)nsb * 128 + ch2);
        const __half2 nvB = *(const __half2*)(v1 + (size_t)nsb * 128 + ch2);

        const float2 kAf = __half22float2(kA);
        const float2 kBf = __half22float2(kB);
        const float2 vAf = __half22float2(vA);
        const float2 vBf = __half22float2(vB);

        float pA = qv.x * kAf.x + qv.y * kAf.y;
        float pB = qv.x * kBf.x + qv.y * kBf.y;
        pA += __shfl_xor(pA, 8, 16); pB += __shfl_xor(pB, 8, 16);
        pA += __shfl_xor(pA, 4, 16); pB += __shfl_xor(pB, 4, 16);
        pA += __shfl_xor(pA, 2, 16); pB += __shfl_xor(pB, 2, 16);
        pA += __shfl_xor(pA, 1, 16); pB += __shfl_xor(pB, 1, 16);

        const float exA = __expf(pA - 4.0f);
        accA.x += exA * vAf.x;
        accA.y += exA * vAf.y;
        sA += exA;

        const float exB = __expf(pB - 4.0f);
        accB.x += exB * vBf.x;
        accB.y += exB * vBf.y;
        sB += exB;

        kA = nkA; vA = nvA; kB = nkB; vB = nvB;
        i = ni;
    }
    if (i < end) {  // odd tail -> chain A
        const float2 kAf = __half22float2(kA);
        const float2 vAf = __half22float2(vA);
        float pA = qv.x * kAf.x + qv.y * kAf.y;
        pA += __shfl_xor(pA, 8, 16);
        pA += __shfl_xor(pA, 4, 16);
        pA += __shfl_xor(pA, 2, 16);
        pA += __shfl_xor(pA, 1, 16);
        const float exA = __expf(pA - 4.0f);
        accA.x += exA * vAf.x;
        accA.y += exA * vAf.y;
        sA += exA;
    }

    const float inv = 1.f / (sA + sB + 1e-16f);
    float2 o = __half22float2(*(const __half2*)(skiph + (size_t)d * 128 + ch2));
    o.x = elu1(o.x + (accA.x + accB.x) * inv);
    o.y = elu1(o.y + (accA.y + accB.y) * inv);
    *(__half2*)(hb + (size_t)d * 128 + ch2) = __floats2half2_rn(o.x, o.y);
}

// ---------- layer-2 projections via MFMA: h[N,128] @ W2t^T + bias2 ----------
// ct tile = matrix: 0->q2h[N][16], 1->k half of kv2h, 2->v half, 3->s2 (f32 out).
__global__ __launch_bounds__(128) void node_l2_mfma(
    const __half* __restrict__ hb, const __half* __restrict__ W2t,
    const float* __restrict__ bias2,
    __half* __restrict__ q2h, __half* __restrict__ kv2h,
    float* __restrict__ out)
{
    const int t = threadIdx.x;
    const int wave = t >> 6;
    const int lane = t & 63;
    const int l = lane & 15;
    const int g = lane >> 4;  // 0..3
    const int wrow0 = blockIdx.x * 128 + wave * 64;
    if (wrow0 >= NN) return;
    const bool full = (wrow0 + 64 <= NN);

    f16x8 hf[4][4];
    #pragma unroll
    for (int rt = 0; rt < 4; ++rt) {
        int arow = wrow0 + rt * 16 + l;
        if (!full && arow >= NN) arow = NN - 1;
        #pragma unroll
        for (int kk = 0; kk < 4; ++kk)
            hf[rt][kk] = *(const f16x8*)((const _Float16*)hb + (size_t)arow * 128 + kk * 32 + g * 8);
    }

    #pragma unroll
    for (int ct = 0; ct < 4; ++ct) {
        const int col = ct * 16 + l;
        f16x8 wf[4];
        #pragma unroll
        for (int kk = 0; kk < 4; ++kk)
            wf[kk] = *(const f16x8*)((const _Float16*)W2t + (size_t)col * 128 + kk * 32 + g * 8);

        f32x4 acc[4];
        #pragma unroll
        for (int rt = 0; rt < 4; ++rt) acc[rt] = (f32x4){0.f, 0.f, 0.f, 0.f};
        #pragma unroll
        for (int kk = 0; kk < 4; ++kk)
            #pragma unroll
            for (int rt = 0; rt < 4; ++rt)
                acc[rt] = __builtin_amdgcn_mfma_f32_16x16x32_f16(wf[kk], hf[rt][kk], acc[rt], 0, 0, 0);

        const int c0 = g * 4;  // within-tile column base
        const float4 bias = *(const float4*)(bias2 + ct * 16 + c0);
        #pragma unroll
        for (int rt = 0; rt < 4; ++rt) {
            const int row = wrow0 + rt * 16 + l;
            if (full || row < NN) {
                float4 r;
                r.x = acc[rt][0] + bias.x;
                r.y = acc[rt][1] + bias.y;
                r.z = acc[rt][2] + bias.z;
                r.w = acc[rt][3] + bias.w;
                if (ct == 3) {
                    // s2 -> out f32 [N][10]; only cols 0..9 exist
                    if (g < 2) {
                        *(float4*)(out + (size_t)row * 10 + c0) = r;
                    } else if (g == 2) {
                        out[(size_t)row * 10 + 8] = r.x;
                        out[(size_t)row * 10 + 9] = r.y;
                    }
                } else {
                    __half* p = ct == 0 ? q2h + (size_t)row * 16 + c0
                              : kv2h + (size_t)row * 32 + (ct == 2 ? 16 : 0) + c0;
                    __half2 h01 = __floats2half2_rn(r.x, r.y);
                    __half2 h23 = __floats2half2_rn(r.z, r.w);
                    uint2 u;
                    u.x = *(unsigned*)&h01;
                    u.y = *(unsigned*)&h23;
                    *(uint2*)p = u;
                }
            }
        }
    }
}

// ---------- layer-2 fused attention: 8 lanes/dst, half2 loads, zero predication ----
// q2h/kv2h channels 10..15 are exact zeros -> 8-lane shfl dot is exact; pad lanes
// accumulate zeros. 32 dsts per 256-thread block; per-edge loads halved.
__global__ __launch_bounds__(256) void node_attn2(
    const __half* __restrict__ q2h, const __half* __restrict__ kv2h,
    const int* __restrict__ rowptr, const int* __restrict__ esrc,
    float* __restrict__ out)  // pre-loaded with skip (h @ Ws2 + bs2)
{
    const int t = threadIdx.x;
    const int d = blockIdx.x * 32 + (t >> 3);
    if (d >= NN) return;
    const int c = t & 7;  // channel pair (2c, 2c+1)
    const int beg = rowptr[d];
    const int end = rowptr[d + 1];

    float2 qv = __half22float2(*(const __half2*)(q2h + (size_t)d * 16 + 2 * c));
    qv.x *= 0.31622776601683794f;  // fold 1/sqrt(10)
    qv.y *= 0.31622776601683794f;

    float2 accA = make_float2(0.f, 0.f), accB = make_float2(0.f, 0.f);
    float sA = 0.f, sB = 0.f;

    int i = beg;
    int sa = (i < end) ? esrc[i] : 0;
    int sb = (i + 1 < end) ? esrc[i + 1] : 0;
    __half2 kA = *(const __half2*)(kv2h + (size_t)sa * 32 + 2 * c);
    __half2 vA = *(const __half2*)(kv2h + (size_t)sa * 32 + 16 + 2 * c);
    __half2 kB = *(const __half2*)(kv2h + (size_t)sb * 32 + 2 * c);
    __half2 vB = *(const __half2*)(kv2h + (size_t)sb * 32 + 16 + 2 * c);

    while (i + 1 < end) {
        const int ni = i + 2;
        const int nsa = (ni < end) ? esrc[ni] : 0;
        const int nsb = (ni + 1 < end) ? esrc[ni + 1] : 0;
        const __half2 nkA = *(const __half2*)(kv2h + (size_t)nsa * 32 + 2 * c);
        const __half2 nvA = *(const __half2*)(kv2h + (size_t)nsa * 32 + 16 + 2 * c);
        const __half2 nkB = *(const __half2*)(kv2h + (size_t)nsb * 32 + 2 * c);
        const __half2 nvB = *(const __half2*)(kv2h + (size_t)nsb * 32 + 16 + 2 * c);

        const float2 kAf = __half22float2(kA);
        const float2 kBf = __half22float2(kB);
        const float2 vAf = __half22float2(vA);
        const float2 vBf = __half22float2(vB);

        float pA = qv.x * kAf.x + qv.y * kAf.y;
        float pB = qv.x * kBf.x + qv.y * kBf.y;
        pA += __shfl_xor(pA, 4, 8); pB += __shfl_xor(pB, 4, 8);
        pA += __shfl_xor(pA, 2, 8); pB += __shfl_xor(pB, 2, 8);
        pA += __shfl_xor(pA, 1, 8); pB += __shfl_xor(pB, 1, 8);

        const float exA = __expf(pA - 2.0f);
        accA.x += exA * vAf.x;
        accA.y += exA * vAf.y;
        sA += exA;

        const float exB = __expf(pB - 2.0f);
        accB.x += exB * vBf.x;
        accB.y += exB * vBf.y;
        sB += exB;

        kA = nkA; vA = nvA; kB = nkB; vB = nvB;
        i = ni;
    }
    if (i < end) {
        const float2 kAf = __half22float2(kA);
        const float2 vAf = __half22float2(vA);
        float pA = qv.x * kAf.x + qv.y * kAf.y;
        pA += __shfl_xor(pA, 4, 8);
        pA += __shfl_xor(pA, 2, 8);
        pA += __shfl_xor(pA, 1, 8);
        const float exA = __expf(pA - 2.0f);
        accA.x += exA * vAf.x;
        accA.y += exA * vAf.y;
        sA += exA;
    }

    if (c < 5) {  // channels 2c, 2c+1 in 0..9
        const float inv = 1.f / (sA + sB + 1e-16f);
        float2 o = *(float2*)(out + (size_t)d * 10 + 2 * c);
        o.x += (accA.x + accB.x) * inv;
        o.y += (accA.y + accB.y) * inv;
        *(float2*)(out + (size_t)d * 10 + 2 * c) = o;
    }
}

extern "C" void kernel_launch(void* const* d_in, const int* in_sizes, int n_in,
                              void* d_out, int out_size, void* d_ws, size_t ws_size,
                              hipStream_t stream) {
    const float* x   = (const float*)d_in[0];
    const int*   ei  = (const int*)d_in[1];
    const float* Wq1 = (const float*)d_in[2];  const float* bq1 = (const float*)d_in[3];
    const float* Wk1 = (const float*)d_in[4];  const float* bk1 = (const float*)d_in[5];
    const float* Wv1 = (const float*)d_in[6];  const float* bv1 = (const float*)d_in[7];
    const float* Ws1 = (const float*)d_in[8];  const float* bs1 = (const float*)d_in[9];
    const float* Wq2 = (const float*)d_in[10]; const float* bq2 = (const float*)d_in[11];
    const float* Wk2 = (const float*)d_in[12]; const float* bk2 = (const float*)d_in[13];
    const float* Wv2 = (const float*)d_in[14]; const float* bv2 = (const float*)d_in[15];
    const float* Ws2 = (const float*)d_in[16]; const float* bs2 = (const float*)d_in[17];
    float* out = (float*)d_out;

    const int* src = ei;
    const int* dst = ei + EE;

    // workspace carve
    __half* q1h   = (__half*)d_ws;                      // N*128 f16
    __half* k1h   = q1h + (size_t)NN * 128;             // N*128 f16
    __half* v1h   = k1h + (size_t)NN * 128;             // N*128 f16
    __half* skiph = v1h + (size_t)NN * 128;             // N*128 f16 (x @ Ws + bs)
    __half* hb    = skiph + (size_t)NN * 128;           // N*128 f16 (h)
    __half* Wt    = hb + (size_t)NN * 128;              // 4*128*128 f16
    __half* W2t   = Wt + 4 * 128 * 128;                 // 64*128 f16
    __half* q2h   = W2t + 64 * 128;                     // N*16 f16 (padded)
    __half* kv2h  = q2h + (size_t)NN * 16;              // N*32 f16 (k|v packed, 64B/node)
    float* bias2  = (float*)(kv2h + (size_t)NN * 32);   // 64 f32
    int* deg      = (int*)(bias2 + 64);                 // N
    int* rowptr   = deg + NN;                           // N+1
    int* cursor   = rowptr + NN + 1;                    // N
    int* bsum     = cursor + NN;                        // NB
    int* esrc     = bsum + NB;                          // E (src sorted by dst)

    // prep + CSR build
    hipMemsetAsync(deg, 0, (size_t)NN * sizeof(int), stream);
    deg_count<<<EE / 256, 256, 0, stream>>>(dst, deg);
    build_weights<<<64, 256, 0, stream>>>(Wq1, Wk1, Wv1, Ws1,
                                          Wq2, bq2, Wk2, bk2, Wv2, bv2, Ws2, bs2,
                                          Wt, W2t, bias2);
    block_sums<<<NB, 256, 0, stream>>>(deg, bsum);
    scan_bsums<<<1, 256, 0, stream>>>(bsum);
    write_rowptr<<<NB, 256, 0, stream>>>(deg, bsum, rowptr, cursor);
    scatter_edges<<<EE / 256, 256, 0, stream>>>(src, dst, cursor, esrc);

    // layer 1 projections via MFMA: one mat per block, 12 waves/CU
    gemm_l1_mfma<<<dim3((NN + 127) / 128, 4), 128, 0, stream>>>(
        x, Wt, bq1, bk1, bv1, bs1, q1h, k1h, v1h, skiph);

    // fused layer-1 attention + skip + ELU -> h fp16
    node_attn1<<<NN / 4, 256, 0, stream>>>(q1h, k1h, v1h, rowptr, esrc, skiph, hb);

    // layer-2 projections via MFMA (s2 written directly to d_out)
    node_l2_mfma<<<(NN + 127) / 128, 128, 0, stream>>>(hb, W2t, bias2, q2h, kv2h, out);

    // fused layer-2 attention (8 lanes/dst, half2)
    node_attn2<<<(NN + 31) / 32, 256, 0, stream>>>(q2h, kv2h, rowptr, esrc, out);
}

// Round 15
// 220.458 us; speedup vs baseline: 1.0575x; 1.0575x over previous
//
#include <hip/hip_runtime.h>
#include <hip/hip_fp16.h>
#include <math.h>

#define NN 50000
#define EE 800000
#define NB 196  // ceil(NN/256)
// IN_DIM = 128, HEADS*HIDDEN = 128, NUM_CLASSES = 10

typedef _Float16 f16x8 __attribute__((ext_vector_type(8)));
typedef float f32x4 __attribute__((ext_vector_type(4)));

__device__ inline float elu1(float x) { return x > 0.f ? x : expm1f(x); }

// ---------- prep: W1 transpose (f16) + W2 pack (f16, zero-padded) in one kernel ----------
__global__ __launch_bounds__(256) void build_weights(
    const float* __restrict__ Wq, const float* __restrict__ Wk,
    const float* __restrict__ Wv, const float* __restrict__ Ws,
    const float* __restrict__ Wq2, const float* __restrict__ bq2,
    const float* __restrict__ Wk2, const float* __restrict__ bk2,
    const float* __restrict__ Wv2, const float* __restrict__ bv2,
    const float* __restrict__ Ws2, const float* __restrict__ bs2,
    __half* __restrict__ Wt, __half* __restrict__ W2t, float* __restrict__ bias2)
{
    // part A (blocks 0..31): W2[128][10] x4 -> W2t[64][128] zero-padded + bias2[64]
    const int idx = blockIdx.x * 256 + threadIdx.x;
    if (idx < 8192) {
        const int col = idx >> 7, k = idx & 127;
        const int m = col >> 4, j = col & 15;
        const float* W = m == 0 ? Wq2 : m == 1 ? Wk2 : m == 2 ? Wv2 : Ws2;
        W2t[idx] = (__half)(j < 10 ? W[k * 10 + j] : 0.f);
    }
    if (idx < 64) {
        const int m = idx >> 4, j = idx & 15;
        const float* b = m == 0 ? bq2 : m == 1 ? bk2 : m == 2 ? bv2 : bs2;
        bias2[idx] = j < 10 ? b[j] : 0.f;
    }
    // part B (all 64 blocks): W1[k][c] -> Wt[mat][c][k] f16 via LDS tile transpose
    __shared__ float tile[32][33];
    const int mat = blockIdx.x >> 4;
    const int tid = blockIdx.x & 15;
    const int k0 = (tid >> 2) * 32, c0 = (tid & 3) * 32;
    const float* W = mat == 0 ? Wq : mat == 1 ? Wk : mat == 2 ? Wv : Ws;
    const int r = threadIdx.x >> 5;   // 0..7
    const int c = threadIdx.x & 31;
    for (int rr = r; rr < 32; rr += 8) tile[rr][c] = W[(size_t)(k0 + rr) * 128 + c0 + c];
    __syncthreads();
    for (int rr = r; rr < 32; rr += 8)
        Wt[((size_t)mat * 128 + c0 + rr) * 128 + k0 + c] = (__half)tile[c][rr];
}

// ---------- CSR build: multi-block scan, scatter (histogram fused into gemm) ----------
__global__ __launch_bounds__(256) void block_sums(
    const int* __restrict__ deg, int* __restrict__ bsum)
{
    __shared__ int ws[4];
    const int t = threadIdx.x;
    const int idx = blockIdx.x * 256 + t;
    int d = (idx < NN) ? deg[idx] : 0;
    #pragma unroll
    for (int off = 32; off; off >>= 1) d += __shfl_down(d, off, 64);
    if ((t & 63) == 0) ws[t >> 6] = d;
    __syncthreads();
    if (t == 0) bsum[blockIdx.x] = ws[0] + ws[1] + ws[2] + ws[3];
}

__global__ __launch_bounds__(256) void scan_bsums(int* __restrict__ bsum)
{
    __shared__ int s[256];
    const int t = threadIdx.x;
    int v = (t < NB) ? bsum[t] : 0;
    s[t] = v;
    __syncthreads();
    for (int off = 1; off < 256; off <<= 1) {
        int u = (t >= off) ? s[t - off] : 0;
        __syncthreads();
        s[t] += u;
        __syncthreads();
    }
    if (t < NB) bsum[t] = (t == 0) ? 0 : s[t - 1];
}

__global__ __launch_bounds__(256) void write_rowptr(
    const int* __restrict__ deg, const int* __restrict__ bsum,
    int* __restrict__ rowptr, int* __restrict__ cursor)
{
    __shared__ int s[256];
    const int t = threadIdx.x;
    const int idx = blockIdx.x * 256 + t;
    const int d = (idx < NN) ? deg[idx] : 0;
    s[t] = d;
    __syncthreads();
    for (int off = 1; off < 256; off <<= 1) {
        int u = (t >= off) ? s[t - off] : 0;
        __syncthreads();
        s[t] += u;
        __syncthreads();
    }
    const int excl = ((t == 0) ? 0 : s[t - 1]) + bsum[blockIdx.x];
    if (idx < NN) {
        rowptr[idx] = excl;
        cursor[idx] = excl;
    }
    if (idx == NN - 1) rowptr[NN] = excl + d;  // == EE
}

__global__ __launch_bounds__(256) void scatter_edges(
    const int* __restrict__ src, const int* __restrict__ dst,
    int* __restrict__ cursor, int* __restrict__ esrc)
{
    const int e = blockIdx.x * 256 + threadIdx.x;
    if (e >= EE) return;
    const int d = dst[e];
    const int pos = atomicAdd(&cursor[d], 1);
    esrc[pos] = src[e];
}

// ---------- layer-1 projections via MFMA: 2 mats per block, 32-row waves ----------
// 3128 waves (12/CU) at CONSTANT x-traffic (2x read, 51 MB) — fixes R13's
// grid-limited latency-boundness without R14's 4x x-read regression.
// Dst-degree histogram fused (runs before row-bound return). uint2 8B stores.
__global__ __launch_bounds__(128) void gemm_l1_mfma(
    const float* __restrict__ x, const __half* __restrict__ Wt,
    const float* __restrict__ bq, const float* __restrict__ bk,
    const float* __restrict__ bv, const float* __restrict__ bs,
    const int* __restrict__ dst, int* __restrict__ deg,
    __half* __restrict__ oqh, __half* __restrict__ okh,
    __half* __restrict__ ovh, __half* __restrict__ osh)
{
    const int pair = blockIdx.y;  // 0: mats {0,1}; 1: mats {2,3}
    const int t = threadIdx.x;

    // fused degree histogram: 200192 threads x 4 edges, coalesced
    {
        const int gtid = (blockIdx.y * gridDim.x + blockIdx.x) * 128 + t;
        #pragma unroll
        for (int u = 0; u < 4; ++u) {
            const int e = u * 200192 + gtid;
            if (e < EE) atomicAdd(&deg[dst[e]], 1);
        }
    }

    const int wave = t >> 6;
    const int lane = t & 63;
    const int l = lane & 15;
    const int g = lane >> 4;  // 0..3
    const int wrow0 = blockIdx.x * 64 + wave * 32;
    if (wrow0 >= NN) return;
    const bool full = (wrow0 + 32 <= NN);

    // x fragments (B operand): f32 load + in-register cvt; 2 row-tiles per wave
    f16x8 xf[2][4];
    #pragma unroll
    for (int rt = 0; rt < 2; ++rt) {
        int arow = wrow0 + rt * 16 + l;
        if (!full && arow >= NN) arow = NN - 1;  // clamp: garbage rows never stored
        #pragma unroll
        for (int kk = 0; kk < 4; ++kk) {
            const float* xp = x + (size_t)arow * 128 + kk * 32 + g * 8;
            const float4 a = *(const float4*)xp;
            const float4 b = *(const float4*)(xp + 4);
            f16x8 f;
            f[0] = (_Float16)a.x; f[1] = (_Float16)a.y;
            f[2] = (_Float16)a.z; f[3] = (_Float16)a.w;
            f[4] = (_Float16)b.x; f[5] = (_Float16)b.y;
            f[6] = (_Float16)b.z; f[7] = (_Float16)b.w;
            xf[rt][kk] = f;
        }
    }

    for (int mi = 0; mi < 2; ++mi) {
        const int mat = pair * 2 + mi;
        const float* b = mat == 0 ? bq : mat == 1 ? bk : mat == 2 ? bv : bs;
        __half* o = mat == 0 ? oqh : mat == 1 ? okh : mat == 2 ? ovh : osh;
        const _Float16* wt = (const _Float16*)Wt + (size_t)mat * 128 * 128;

        f16x8 wf[4], wfn[4];
        #pragma unroll
        for (int kk = 0; kk < 4; ++kk)
            wf[kk] = *(const f16x8*)(wt + (size_t)l * 128 + kk * 32 + g * 8);

        for (int ct = 0; ct < 8; ++ct) {
            if (ct < 7) {
                const int ncol = (ct + 1) * 16 + l;
                #pragma unroll
                for (int kk = 0; kk < 4; ++kk)
                    wfn[kk] = *(const f16x8*)(wt + (size_t)ncol * 128 + kk * 32 + g * 8);
            }
            f32x4 acc[2];
            #pragma unroll
            for (int rt = 0; rt < 2; ++rt) acc[rt] = (f32x4){0.f, 0.f, 0.f, 0.f};
            #pragma unroll
            for (int kk = 0; kk < 4; ++kk)
                #pragma unroll
                for (int rt = 0; rt < 2; ++rt)
                    acc[rt] = __builtin_amdgcn_mfma_f32_16x16x32_f16(wf[kk], xf[rt][kk], acc[rt], 0, 0, 0);

            const int col0 = ct * 16 + g * 4;
            const float4 bias = *(const float4*)(b + col0);
            #pragma unroll
            for (int rt = 0; rt < 2; ++rt) {
                const int row = wrow0 + rt * 16 + l;
                if (full || row < NN) {
                    __half2 h01 = __floats2half2_rn(acc[rt][0] + bias.x, acc[rt][1] + bias.y);
                    __half2 h23 = __floats2half2_rn(acc[rt][2] + bias.z, acc[rt][3] + bias.w);
                    uint2 u;
                    u.x = *(unsigned*)&h01;
                    u.y = *(unsigned*)&h23;
                    *(uint2*)(o + (size_t)row * 128 + col0) = u;  // one 8B store
                }
            }
            #pragma unroll
            for (int kk = 0; kk < 4; ++kk) wf[kk] = wfn[kk];
        }
    }
}

// ---------- layer-1 fused attention + skip + ELU -> h (fp16) ----------
// static-shift softmax (shift-invariant; logits ~ N(0,1) so exp(lg-4) is safe).
__global__ __launch_bounds__(256) void node_attn1(
    const __half* __restrict__ q1, const __half* __restrict__ k1,
    const __half* __restrict__ v1,
    const int* __restrict__ rowptr, const int* __restrict__ esrc,
    const __half* __restrict__ skiph,  // x @ Ws + bs (f16)
    __half* __restrict__ hb)           // out: h = elu(skip + attn), fp16
{
    const int t = threadIdx.x;
    const int wid = __builtin_amdgcn_readfirstlane(t >> 6);
    const int d = blockIdx.x * 4 + wid;
    if (d >= NN) return;
    const int lane = t & 63;
    const int ch2 = lane << 1;

    const int beg = rowptr[d];
    const int end = rowptr[d + 1];

    float2 qv = __half22float2(*(const __half2*)(q1 + (size_t)d * 128 + ch2));
    qv.x *= 0.17677669529663687f;  // fold 1/sqrt(32) into q
    qv.y *= 0.17677669529663687f;

    float2 accA = make_float2(0.f, 0.f), accB = make_float2(0.f, 0.f);
    float sA = 0.f, sB = 0.f;

    int i = beg;
    int sa = (i < end) ? esrc[i] : 0;
    int sb = (i + 1 < end) ? esrc[i + 1] : 0;
    __half2 kA = *(const __half2*)(k1 + (size_t)sa * 128 + ch2);
    __half2 vA = *(const __half2*)(v1 + (size_t)sa * 128 + ch2);
    __half2 kB = *(const __half2*)(k1 + (size_t)sb * 128 + ch2);
    __half2 vB = *(const __half2*)(v1 + (size_t)sb * 128 + ch2);

    while (i + 1 < end) {
        const int ni = i + 2;
        const int nsa = (ni < end) ? esrc[ni] : 0;
        const int nsb = (ni + 1 < end) ? esrc[ni + 1] : 0;
        const __half2 nkA = *(const __half2*)(k1 + (size_t)nsa * 128 + ch2);
        const __half2 nvA = *(const __half2*)(v1 + (size_t)nsa * 128 + ch2);
        const __half2 nkB = *(const __half2*)(k1 + (size_t)nsb * 128 + ch2);
        const __half2 nvB = *(const __half2*)(v1 + (size_t)nsb * 128 + ch2);

        const float2 kAf = __half22float2(kA);
        const float2 kBf = __half22float2(kB);
        const float2 vAf = __half22float2(vA);
        const float2 vBf = __half22float2(vB);

        float pA = qv.x * kAf.x + qv.y * kAf.y;
        float pB = qv.x * kBf.x + qv.y * kBf.y;
        pA += __shfl_xor(pA, 8, 16); pB += __shfl_xor(pB, 8, 16);
        pA += __shfl_xor(pA, 4, 16); pB += __shfl_xor(pB, 4, 16);
        pA += __shfl_xor(pA, 2, 16); pB += __shfl_xor(pB, 2, 16);
        pA += __shfl_xor(pA, 1, 16); pB += __shfl_xor(pB, 1, 16);

        const float exA = __expf(pA - 4.0f);
        accA.x += exA * vAf.x;
        accA.y += exA * vAf.y;
        sA += exA;

        const float exB = __expf(pB - 4.0f);
        accB.x += exB * vBf.x;
        accB.y += exB * vBf.y;
        sB += exB;

        kA = nkA; vA = nvA; kB = nkB; vB = nvB;
        i = ni;
    }
    if (i < end) {  // odd tail -> chain A
        const float2 kAf = __half22float2(kA);
        const float2 vAf = __half22float2(vA);
        float pA = qv.x * kAf.x + qv.y * kAf.y;
        pA += __shfl_xor(pA, 8, 16);
        pA += __shfl_xor(pA, 4, 16);
        pA += __shfl_xor(pA, 2, 16);
        pA += __shfl_xor(pA, 1, 16);
        const float exA = __expf(pA - 4.0f);
        accA.x += exA * vAf.x;
        accA.y += exA * vAf.y;
        sA += exA;
    }

    const float inv = 1.f / (sA + sB + 1e-16f);
    float2 o = __half22float2(*(const __half2*)(skiph + (size_t)d * 128 + ch2));
    o.x = elu1(o.x + (accA.x + accB.x) * inv);
    o.y = elu1(o.y + (accA.y + accB.y) * inv);
    *(__half2*)(hb + (size_t)d * 128 + ch2) = __floats2half2_rn(o.x, o.y);
}

// ---------- layer-2 projections via MFMA: h[N,128] @ W2t^T + bias2 ----------
// ct tile = matrix: 0->q2h[N][16], 1->k half of kv2h, 2->v half, 3->s2 (f32 out).
__global__ __launch_bounds__(128) void node_l2_mfma(
    const __half* __restrict__ hb, const __half* __restrict__ W2t,
    const float* __restrict__ bias2,
    __half* __restrict__ q2h, __half* __restrict__ kv2h,
    float* __restrict__ out)
{
    const int t = threadIdx.x;
    const int wave = t >> 6;
    const int lane = t & 63;
    const int l = lane & 15;
    const int g = lane >> 4;  // 0..3
    const int wrow0 = blockIdx.x * 128 + wave * 64;
    if (wrow0 >= NN) return;
    const bool full = (wrow0 + 64 <= NN);

    f16x8 hf[4][4];
    #pragma unroll
    for (int rt = 0; rt < 4; ++rt) {
        int arow = wrow0 + rt * 16 + l;
        if (!full && arow >= NN) arow = NN - 1;
        #pragma unroll
        for (int kk = 0; kk < 4; ++kk)
            hf[rt][kk] = *(const f16x8*)((const _Float16*)hb + (size_t)arow * 128 + kk * 32 + g * 8);
    }

    #pragma unroll
    for (int ct = 0; ct < 4; ++ct) {
        const int col = ct * 16 + l;
        f16x8 wf[4];
        #pragma unroll
        for (int kk = 0; kk < 4; ++kk)
            wf[kk] = *(const f16x8*)((const _Float16*)W2t + (size_t)col * 128 + kk * 32 + g * 8);

        f32x4 acc[4];
        #pragma unroll
        for (int rt = 0; rt < 4; ++rt) acc[rt] = (f32x4){0.f, 0.f, 0.f, 0.f};
        #pragma unroll
        for (int kk = 0; kk < 4; ++kk)
            #pragma unroll
            for (int rt = 0; rt < 4; ++rt)
                acc[rt] = __builtin_amdgcn_mfma_f32_16x16x32_f16(wf[kk], hf[rt][kk], acc[rt], 0, 0, 0);

        const int c0 = g * 4;  // within-tile column base
        const float4 bias = *(const float4*)(bias2 + ct * 16 + c0);
        #pragma unroll
        for (int rt = 0; rt < 4; ++rt) {
            const int row = wrow0 + rt * 16 + l;
            if (full || row < NN) {
                float4 r;
                r.x = acc[rt][0] + bias.x;
                r.y = acc[rt][1] + bias.y;
                r.z = acc[rt][2] + bias.z;
                r.w = acc[rt][3] + bias.w;
                if (ct == 3) {
                    // s2 -> out f32 [N][10]; only cols 0..9 exist
                    if (g < 2) {
                        *(float4*)(out + (size_t)row * 10 + c0) = r;
                    } else if (g == 2) {
                        out[(size_t)row * 10 + 8] = r.x;
                        out[(size_t)row * 10 + 9] = r.y;
                    }
                } else {
                    __half* p = ct == 0 ? q2h + (size_t)row * 16 + c0
                              : kv2h + (size_t)row * 32 + (ct == 2 ? 16 : 0) + c0;
                    __half2 h01 = __floats2half2_rn(r.x, r.y);
                    __half2 h23 = __floats2half2_rn(r.z, r.w);
                    uint2 u;
                    u.x = *(unsigned*)&h01;
                    u.y = *(unsigned*)&h23;
                    *(uint2*)p = u;
                }
            }
        }
    }
}

// ---------- layer-2 fused attention: 8 lanes/dst, half2 loads, zero predication ----
// q2h/kv2h channels 10..15 are exact zeros -> 8-lane shfl dot is exact; pad lanes
// accumulate zeros. 32 dsts per 256-thread block; per-edge loads halved.
__global__ __launch_bounds__(256) void node_attn2(
    const __half* __restrict__ q2h, const __half* __restrict__ kv2h,
    const int* __restrict__ rowptr, const int* __restrict__ esrc,
    float* __restrict__ out)  // pre-loaded with skip (h @ Ws2 + bs2)
{
    const int t = threadIdx.x;
    const int d = blockIdx.x * 32 + (t >> 3);
    if (d >= NN) return;
    const int c = t & 7;  // channel pair (2c, 2c+1)
    const int beg = rowptr[d];
    const int end = rowptr[d + 1];

    float2 qv = __half22float2(*(const __half2*)(q2h + (size_t)d * 16 + 2 * c));
    qv.x *= 0.31622776601683794f;  // fold 1/sqrt(10)
    qv.y *= 0.31622776601683794f;

    float2 accA = make_float2(0.f, 0.f), accB = make_float2(0.f, 0.f);
    float sA = 0.f, sB = 0.f;

    int i = beg;
    int sa = (i < end) ? esrc[i] : 0;
    int sb = (i + 1 < end) ? esrc[i + 1] : 0;
    __half2 kA = *(const __half2*)(kv2h + (size_t)sa * 32 + 2 * c);
    __half2 vA = *(const __half2*)(kv2h + (size_t)sa * 32 + 16 + 2 * c);
    __half2 kB = *(const __half2*)(kv2h + (size_t)sb * 32 + 2 * c);
    __half2 vB = *(const __half2*)(kv2h + (size_t)sb * 32 + 16 + 2 * c);

    while (i + 1 < end) {
        const int ni = i + 2;
        const int nsa = (ni < end) ? esrc[ni] : 0;
        const int nsb = (ni + 1 < end) ? esrc[ni + 1] : 0;
        const __half2 nkA = *(const __half2*)(kv2h + (size_t)nsa * 32 + 2 * c);
        const __half2 nvA = *(const __half2*)(kv2h + (size_t)nsa * 32 + 16 + 2 * c);
        const __half2 nkB = *(const __half2*)(kv2h + (size_t)nsb * 32 + 2 * c);
        const __half2 nvB = *(const __half2*)(kv2h + (size_t)nsb * 32 + 16 + 2 * c);

        const float2 kAf = __half22float2(kA);
        const float2 kBf = __half22float2(kB);
        const float2 vAf = __half22float2(vA);
        const float2 vBf = __half22float2(vB);

        float pA = qv.x * kAf.x + qv.y * kAf.y;
        float pB = qv.x * kBf.x + qv.y * kBf.y;
        pA += __shfl_xor(pA, 4, 8); pB += __shfl_xor(pB, 4, 8);
        pA += __shfl_xor(pA, 2, 8); pB += __shfl_xor(pB, 2, 8);
        pA += __shfl_xor(pA, 1, 8); pB += __shfl_xor(pB, 1, 8);

        const float exA = __expf(pA - 2.0f);
        accA.x += exA * vAf.x;
        accA.y += exA * vAf.y;
        sA += exA;

        const float exB = __expf(pB - 2.0f);
        accB.x += exB * vBf.x;
        accB.y += exB * vBf.y;
        sB += exB;

        kA = nkA; vA = nvA; kB = nkB; vB = nvB;
        i = ni;
    }
    if (i < end) {
        const float2 kAf = __half22float2(kA);
        const float2 vAf = __half22float2(vA);
        float pA = qv.x * kAf.x + qv.y * kAf.y;
        pA += __shfl_xor(pA, 4, 8);
        pA += __shfl_xor(pA, 2, 8);
        pA += __shfl_xor(pA, 1, 8);
        const float exA = __expf(pA - 2.0f);
        accA.x += exA * vAf.x;
        accA.y += exA * vAf.y;
        sA += exA;
    }

    if (c < 5) {  // channels 2c, 2c+1 in 0..9
        const float inv = 1.f / (sA + sB + 1e-16f);
        float2 o = *(float2*)(out + (size_t)d * 10 + 2 * c);
        o.x += (accA.x + accB.x) * inv;
        o.y += (accA.y + accB.y) * inv;
        *(float2*)(out + (size_t)d * 10 + 2 * c) = o;
    }
}

extern "C" void kernel_launch(void* const* d_in, const int* in_sizes, int n_in,
                              void* d_out, int out_size, void* d_ws, size_t ws_size,
                              hipStream_t stream) {
    const float* x   = (const float*)d_in[0];
    const int*   ei  = (const int*)d_in[1];
    const float* Wq1 = (const float*)d_in[2];  const float* bq1 = (const float*)d_in[3];
    const float* Wk1 = (const float*)d_in[4];  const float* bk1 = (const float*)d_in[5];
    const float* Wv1 = (const float*)d_in[6];  const float* bv1 = (const float*)d_in[7];
    const float* Ws1 = (const float*)d_in[8];  const float* bs1 = (const float*)d_in[9];
    const float* Wq2 = (const float*)d_in[10]; const float* bq2 = (const float*)d_in[11];
    const float* Wk2 = (const float*)d_in[12]; const float* bk2 = (const float*)d_in[13];
    const float* Wv2 = (const float*)d_in[14]; const float* bv2 = (const float*)d_in[15];
    const float* Ws2 = (const float*)d_in[16]; const float* bs2 = (const float*)d_in[17];
    float* out = (float*)d_out;

    const int* src = ei;
    const int* dst = ei + EE;

    // workspace carve
    __half* q1h   = (__half*)d_ws;                      // N*128 f16
    __half* k1h   = q1h + (size_t)NN * 128;             // N*128 f16
    __half* v1h   = k1h + (size_t)NN * 128;             // N*128 f16
    __half* skiph = v1h + (size_t)NN * 128;             // N*128 f16 (x @ Ws + bs)
    __half* hb    = skiph + (size_t)NN * 128;           // N*128 f16 (h)
    __half* Wt    = hb + (size_t)NN * 128;              // 4*128*128 f16
    __half* W2t   = Wt + 4 * 128 * 128;                 // 64*128 f16
    __half* q2h   = W2t + 64 * 128;                     // N*16 f16 (padded)
    __half* kv2h  = q2h + (size_t)NN * 16;              // N*32 f16 (k|v packed, 64B/node)
    float* bias2  = (float*)(kv2h + (size_t)NN * 32);   // 64 f32
    int* deg      = (int*)(bias2 + 64);                 // N
    int* rowptr   = deg + NN;                           // N+1
    int* cursor   = rowptr + NN + 1;                    // N
    int* bsum     = cursor + NN;                        // NB
    int* esrc     = bsum + NB;                          // E (src sorted by dst)

    // prep
    hipMemsetAsync(deg, 0, (size_t)NN * sizeof(int), stream);
    build_weights<<<64, 256, 0, stream>>>(Wq1, Wk1, Wv1, Ws1,
                                          Wq2, bq2, Wk2, bk2, Wv2, bv2, Ws2, bs2,
                                          Wt, W2t, bias2);

    // layer 1 projections via MFMA (2 mats/block, 32-row waves, fused histogram)
    gemm_l1_mfma<<<dim3((NN + 63) / 64, 2), 128, 0, stream>>>(
        x, Wt, bq1, bk1, bv1, bs1, dst, deg, q1h, k1h, v1h, skiph);

    // CSR build (reused by both layers)
    block_sums<<<NB, 256, 0, stream>>>(deg, bsum);
    scan_bsums<<<1, 256, 0, stream>>>(bsum);
    write_rowptr<<<NB, 256, 0, stream>>>(deg, bsum, rowptr, cursor);
    scatter_edges<<<EE / 256, 256, 0, stream>>>(src, dst, cursor, esrc);

    // fused layer-1 attention + skip + ELU -> h fp16
    node_attn1<<<NN / 4, 256, 0, stream>>>(q1h, k1h, v1h, rowptr, esrc, skiph, hb);

    // layer-2 projections via MFMA (s2 written directly to d_out)
    node_l2_mfma<<<(NN + 127) / 128, 128, 0, stream>>>(hb, W2t, bias2, q2h, kv2h, out);

    // fused layer-2 attention (8 lanes/dst, half2)
    node_attn2<<<(NN + 31) / 32, 256, 0, stream>>>(q2h, kv2h, rowptr, esrc, out);
}

// Round 16
// 217.758 us; speedup vs baseline: 1.0707x; 1.0124x over previous
//
#include <hip/hip_runtime.h>
#include <hip/hip_fp16.h>
#include <math.h>

#define NN 50000
#define EE 800000
#define NB 196  // ceil(NN/256)
// IN_DIM = 128, HEADS*HIDDEN = 128, NUM_CLASSES = 10

typedef _Float16 f16x8 __attribute__((ext_vector_type(8)));
typedef float f32x4 __attribute__((ext_vector_type(4)));

__device__ inline float elu1(float x) { return x > 0.f ? x : expm1f(x); }

// ---------- prep: W1 transpose (f16) + W2 pack (f16, zero-padded) in one kernel ----------
__global__ __launch_bounds__(256) void build_weights(
    const float* __restrict__ Wq, const float* __restrict__ Wk,
    const float* __restrict__ Wv, const float* __restrict__ Ws,
    const float* __restrict__ Wq2, const float* __restrict__ bq2,
    const float* __restrict__ Wk2, const float* __restrict__ bk2,
    const float* __restrict__ Wv2, const float* __restrict__ bv2,
    const float* __restrict__ Ws2, const float* __restrict__ bs2,
    __half* __restrict__ Wt, __half* __restrict__ W2t, float* __restrict__ bias2)
{
    // part A (blocks 0..31): W2[128][10] x4 -> W2t[64][128] zero-padded + bias2[64]
    const int idx = blockIdx.x * 256 + threadIdx.x;
    if (idx < 8192) {
        const int col = idx >> 7, k = idx & 127;
        const int m = col >> 4, j = col & 15;
        const float* W = m == 0 ? Wq2 : m == 1 ? Wk2 : m == 2 ? Wv2 : Ws2;
        W2t[idx] = (__half)(j < 10 ? W[k * 10 + j] : 0.f);
    }
    if (idx < 64) {
        const int m = idx >> 4, j = idx & 15;
        const float* b = m == 0 ? bq2 : m == 1 ? bk2 : m == 2 ? bv2 : bs2;
        bias2[idx] = j < 10 ? b[j] : 0.f;
    }
    // part B (all 64 blocks): W1[k][c] -> Wt[mat][c][k] f16 via LDS tile transpose
    __shared__ float tile[32][33];
    const int mat = blockIdx.x >> 4;
    const int tid = blockIdx.x & 15;
    const int k0 = (tid >> 2) * 32, c0 = (tid & 3) * 32;
    const float* W = mat == 0 ? Wq : mat == 1 ? Wk : mat == 2 ? Wv : Ws;
    const int r = threadIdx.x >> 5;   // 0..7
    const int c = threadIdx.x & 31;
    for (int rr = r; rr < 32; rr += 8) tile[rr][c] = W[(size_t)(k0 + rr) * 128 + c0 + c];
    __syncthreads();
    for (int rr = r; rr < 32; rr += 8)
        Wt[((size_t)mat * 128 + c0 + rr) * 128 + k0 + c] = (__half)tile[c][rr];
}

// ---------- CSR build: histogram STANDALONE (fusing into MFMA kernel cost ~15-20us:
// R13/R15 gemm=74-76us with fused hist at both 13% and 28% occupancy; R12/R14 <59 without) ----------
__global__ __launch_bounds__(256) void deg_count(
    const int* __restrict__ dst, int* __restrict__ deg)
{
    const int e = blockIdx.x * 256 + threadIdx.x;
    if (e >= EE) return;
    atomicAdd(&deg[dst[e]], 1);
}

__global__ __launch_bounds__(256) void block_sums(
    const int* __restrict__ deg, int* __restrict__ bsum)
{
    __shared__ int ws[4];
    const int t = threadIdx.x;
    const int idx = blockIdx.x * 256 + t;
    int d = (idx < NN) ? deg[idx] : 0;
    #pragma unroll
    for (int off = 32; off; off >>= 1) d += __shfl_down(d, off, 64);
    if ((t & 63) == 0) ws[t >> 6] = d;
    __syncthreads();
    if (t == 0) bsum[blockIdx.x] = ws[0] + ws[1] + ws[2] + ws[3];
}

__global__ __launch_bounds__(256) void scan_bsums(int* __restrict__ bsum)
{
    __shared__ int s[256];
    const int t = threadIdx.x;
    int v = (t < NB) ? bsum[t] : 0;
    s[t] = v;
    __syncthreads();
    for (int off = 1; off < 256; off <<= 1) {
        int u = (t >= off) ? s[t - off] : 0;
        __syncthreads();
        s[t] += u;
        __syncthreads();
    }
    if (t < NB) bsum[t] = (t == 0) ? 0 : s[t - 1];
}

__global__ __launch_bounds__(256) void write_rowptr(
    const int* __restrict__ deg, const int* __restrict__ bsum,
    int* __restrict__ rowptr, int* __restrict__ cursor)
{
    __shared__ int s[256];
    const int t = threadIdx.x;
    const int idx = blockIdx.x * 256 + t;
    const int d = (idx < NN) ? deg[idx] : 0;
    s[t] = d;
    __syncthreads();
    for (int off = 1; off < 256; off <<= 1) {
        int u = (t >= off) ? s[t - off] : 0;
        __syncthreads();
        s[t] += u;
        __syncthreads();
    }
    const int excl = ((t == 0) ? 0 : s[t - 1]) + bsum[blockIdx.x];
    if (idx < NN) {
        rowptr[idx] = excl;
        cursor[idx] = excl;
    }
    if (idx == NN - 1) rowptr[NN] = excl + d;  // == EE
}

__global__ __launch_bounds__(256) void scatter_edges(
    const int* __restrict__ src, const int* __restrict__ dst,
    int* __restrict__ cursor, int* __restrict__ esrc)
{
    const int e = blockIdx.x * 256 + threadIdx.x;
    if (e >= EE) return;
    const int d = dst[e];
    const int pos = atomicAdd(&cursor[d], 1);
    esrc[pos] = src[e];
}

// ---------- layer-1 projections via MFMA: 2 mats per block, 64-row waves ----------
// Output staged in padded LDS ([128][136] halfs, 272B row stride) then stored as
// FULL 256B rows (one wave instruction = 4 rows x 4 full cache lines) — kills the
// 1.6x partial-line write amplification (WRITE_SIZE 82MB -> ~52MB).
__global__ __launch_bounds__(128) void gemm_l1_mfma(
    const float* __restrict__ x, const __half* __restrict__ Wt,
    const float* __restrict__ bq, const float* __restrict__ bk,
    const float* __restrict__ bv, const float* __restrict__ bs,
    __half* __restrict__ oqh, __half* __restrict__ okh,
    __half* __restrict__ ovh, __half* __restrict__ osh)
{
    __shared__ __half lds[128 * 136];  // 34 KB, row stride 272B (16-aligned)
    const int pair = blockIdx.y;  // 0: mats {0,1}; 1: mats {2,3}
    const int t = threadIdx.x;
    const int wave = t >> 6;
    const int lane = t & 63;
    const int l = lane & 15;
    const int g = lane >> 4;  // 0..3
    const int brow0 = blockIdx.x * 128;
    const int wrow0 = brow0 + wave * 64;

    // x fragments (B operand): f32 load + in-register cvt; lane&15 = row-in-tile
    f16x8 xf[4][4];
    #pragma unroll
    for (int rt = 0; rt < 4; ++rt) {
        int arow = wrow0 + rt * 16 + l;
        if (arow >= NN) arow = NN - 1;  // clamp: garbage rows never stored
        #pragma unroll
        for (int kk = 0; kk < 4; ++kk) {
            const float* xp = x + (size_t)arow * 128 + kk * 32 + g * 8;
            const float4 a = *(const float4*)xp;
            const float4 b = *(const float4*)(xp + 4);
            f16x8 f;
            f[0] = (_Float16)a.x; f[1] = (_Float16)a.y;
            f[2] = (_Float16)a.z; f[3] = (_Float16)a.w;
            f[4] = (_Float16)b.x; f[5] = (_Float16)b.y;
            f[6] = (_Float16)b.z; f[7] = (_Float16)b.w;
            xf[rt][kk] = f;
        }
    }

    for (int mi = 0; mi < 2; ++mi) {
        const int mat = pair * 2 + mi;
        const float* b = mat == 0 ? bq : mat == 1 ? bk : mat == 2 ? bv : bs;
        __half* o = mat == 0 ? oqh : mat == 1 ? okh : mat == 2 ? ovh : osh;
        const _Float16* wt = (const _Float16*)Wt + (size_t)mat * 128 * 128;

        f16x8 wf[4], wfn[4];
        #pragma unroll
        for (int kk = 0; kk < 4; ++kk)
            wf[kk] = *(const f16x8*)(wt + (size_t)l * 128 + kk * 32 + g * 8);

        for (int ct = 0; ct < 8; ++ct) {
            if (ct < 7) {
                const int ncol = (ct + 1) * 16 + l;
                #pragma unroll
                for (int kk = 0; kk < 4; ++kk)
                    wfn[kk] = *(const f16x8*)(wt + (size_t)ncol * 128 + kk * 32 + g * 8);
            }
            f32x4 acc[4];
            #pragma unroll
            for (int rt = 0; rt < 4; ++rt) acc[rt] = (f32x4){0.f, 0.f, 0.f, 0.f};
            #pragma unroll
            for (int kk = 0; kk < 4; ++kk)
                #pragma unroll
                for (int rt = 0; rt < 4; ++rt)
                    acc[rt] = __builtin_amdgcn_mfma_f32_16x16x32_f16(wf[kk], xf[rt][kk], acc[rt], 0, 0, 0);

            const int col0 = ct * 16 + g * 4;
            const float4 bias = *(const float4*)(b + col0);
            #pragma unroll
            for (int rt = 0; rt < 4; ++rt) {
                __half2 h01 = __floats2half2_rn(acc[rt][0] + bias.x, acc[rt][1] + bias.y);
                __half2 h23 = __floats2half2_rn(acc[rt][2] + bias.z, acc[rt][3] + bias.w);
                uint2 u;
                u.x = *(unsigned*)&h01;
                u.y = *(unsigned*)&h23;
                *(uint2*)&lds[(wave * 64 + rt * 16 + l) * 136 + col0] = u;
            }
            #pragma unroll
            for (int kk = 0; kk < 4; ++kk) wf[kk] = wfn[kk];
        }

        __syncthreads();
        // cooperative full-row store: idx = 16B unit; 16 lanes cover one full 256B row
        #pragma unroll
        for (int i = 0; i < 16; ++i) {
            const int idx = i * 128 + t;   // 0..2047
            const int row = idx >> 4;
            const int seg = idx & 15;
            const int grow = brow0 + row;
            if (grow < NN)
                *(uint4*)(o + (size_t)grow * 128 + seg * 8) = *(const uint4*)&lds[row * 136 + seg * 8];
        }
        __syncthreads();
    }
}

// ---------- layer-1 fused attention + skip + ELU -> h (fp16) ----------
// static-shift softmax (shift-invariant; logits ~ N(0,1) so exp(lg-4) is safe).
__global__ __launch_bounds__(256) void node_attn1(
    const __half* __restrict__ q1, const __half* __restrict__ k1,
    const __half* __restrict__ v1,
    const int* __restrict__ rowptr, const int* __restrict__ esrc,
    const __half* __restrict__ skiph,  // x @ Ws + bs (f16)
    __half* __restrict__ hb)           // out: h = elu(skip + attn), fp16
{
    const int t = threadIdx.x;
    const int wid = __builtin_amdgcn_readfirstlane(t >> 6);
    const int d = blockIdx.x * 4 + wid;
    if (d >= NN) return;
    const int lane = t & 63;
    const int ch2 = lane << 1;

    const int beg = rowptr[d];
    const int end = rowptr[d + 1];

    float2 qv = __half22float2(*(const __half2*)(q1 + (size_t)d * 128 + ch2));
    qv.x *= 0.17677669529663687f;  // fold 1/sqrt(32) into q
    qv.y *= 0.17677669529663687f;

    float2 accA = make_float2(0.f, 0.f), accB = make_float2(0.f, 0.f);
    float sA = 0.f, sB = 0.f;

    int i = beg;
    int sa = (i < end) ? esrc[i] : 0;
    int sb = (i + 1 < end) ? esrc[i + 1] : 0;
    __half2 kA = *(const __half2*)(k1 + (size_t)sa * 128 + ch2);
    __half2 vA = *(const __half2*)(v1 + (size_t)sa * 128 + ch2);
    __half2 kB = *(const __half2*)(k1 + (size_t)sb * 128 + ch2);
    __half2 vB = *(const __half2*)(v1 + (size_t)sb * 128 + ch2);

    while (i + 1 < end) {
        const int ni = i + 2;
        const int nsa = (ni < end) ? esrc[ni] : 0;
        const int nsb = (ni + 1 < end) ? esrc[ni + 1] : 0;
        const __half2 nkA = *(const __half2*)(k1 + (size_t)nsa * 128 + ch2);
        const __half2 nvA = *(const __half2*)(v1 + (size_t)nsa * 128 + ch2);
        const __half2 nkB = *(const __half2*)(k1 + (size_t)nsb * 128 + ch2);
        const __half2 nvB = *(const __half2*)(v1 + (size_t)nsb * 128 + ch2);

        const float2 kAf = __half22float2(kA);
        const float2 kBf = __half22float2(kB);
        const float2 vAf = __half22float2(vA);
        const float2 vBf = __half22float2(vB);

        float pA = qv.x * kAf.x + qv.y * kAf.y;
        float pB = qv.x * kBf.x + qv.y * kBf.y;
        pA += __shfl_xor(pA, 8, 16); pB += __shfl_xor(pB, 8, 16);
        pA += __shfl_xor(pA, 4, 16); pB += __shfl_xor(pB, 4, 16);
        pA += __shfl_xor(pA, 2, 16); pB += __shfl_xor(pB, 2, 16);
        pA += __shfl_xor(pA, 1, 16); pB += __shfl_xor(pB, 1, 16);

        const float exA = __expf(pA - 4.0f);
        accA.x += exA * vAf.x;
        accA.y += exA * vAf.y;
        sA += exA;

        const float exB = __expf(pB - 4.0f);
        accB.x += exB * vBf.x;
        accB.y += exB * vBf.y;
        sB += exB;

        kA = nkA; vA = nvA; kB = nkB; vB = nvB;
        i = ni;
    }
    if (i < end) {  // odd tail -> chain A
        const float2 kAf = __half22float2(kA);
        const float2 vAf = __half22float2(vA);
        float pA = qv.x * kAf.x + qv.y * kAf.y;
        pA += __shfl_xor(pA, 8, 16);
        pA += __shfl_xor(pA, 4, 16);
        pA += __shfl_xor(pA, 2, 16);
        pA += __shfl_xor(pA, 1, 16);
        const float exA = __expf(pA - 4.0f);
        accA.x += exA * vAf.x;
        accA.y += exA * vAf.y;
        sA += exA;
    }

    const float inv = 1.f / (sA + sB + 1e-16f);
    float2 o = __half22float2(*(const __half2*)(skiph + (size_t)d * 128 + ch2));
    o.x = elu1(o.x + (accA.x + accB.x) * inv);
    o.y = elu1(o.y + (accA.y + accB.y) * inv);
    *(__half2*)(hb + (size_t)d * 128 + ch2) = __floats2half2_rn(o.x, o.y);
}

// ---------- layer-2 projections via MFMA: h[N,128] @ W2t^T + bias2 ----------
// ct tile = matrix: 0->q2h[N][16], 1->k half of kv2h, 2->v half, 3->s2 (f32 out).
__global__ __launch_bounds__(128) void node_l2_mfma(
    const __half* __restrict__ hb, const __half* __restrict__ W2t,
    const float* __restrict__ bias2,
    __half* __restrict__ q2h, __half* __restrict__ kv2h,
    float* __restrict__ out)
{
    const int t = threadIdx.x;
    const int wave = t >> 6;
    const int lane = t & 63;
    const int l = lane & 15;
    const int g = lane >> 4;  // 0..3
    const int wrow0 = blockIdx.x * 128 + wave * 64;
    if (wrow0 >= NN) return;
    const bool full = (wrow0 + 64 <= NN);

    f16x8 hf[4][4];
    #pragma unroll
    for (int rt = 0; rt < 4; ++rt) {
        int arow = wrow0 + rt * 16 + l;
        if (!full && arow >= NN) arow = NN - 1;
        #pragma unroll
        for (int kk = 0; kk < 4; ++kk)
            hf[rt][kk] = *(const f16x8*)((const _Float16*)hb + (size_t)arow * 128 + kk * 32 + g * 8);
    }

    #pragma unroll
    for (int ct = 0; ct < 4; ++ct) {
        const int col = ct * 16 + l;
        f16x8 wf[4];
        #pragma unroll
        for (int kk = 0; kk < 4; ++kk)
            wf[kk] = *(const f16x8*)((const _Float16*)W2t + (size_t)col * 128 + kk * 32 + g * 8);

        f32x4 acc[4];
        #pragma unroll
        for (int rt = 0; rt < 4; ++rt) acc[rt] = (f32x4){0.f, 0.f, 0.f, 0.f};
        #pragma unroll
        for (int kk = 0; kk < 4; ++kk)
            #pragma unroll
            for (int rt = 0; rt < 4; ++rt)
                acc[rt] = __builtin_amdgcn_mfma_f32_16x16x32_f16(wf[kk], hf[rt][kk], acc[rt], 0, 0, 0);

        const int c0 = g * 4;  // within-tile column base
        const float4 bias = *(const float4*)(bias2 + ct * 16 + c0);
        #pragma unroll
        for (int rt = 0; rt < 4; ++rt) {
            const int row = wrow0 + rt * 16 + l;
            if (full || row < NN) {
                float4 r;
                r.x = acc[rt][0] + bias.x;
                r.y = acc[rt][1] + bias.y;
                r.z = acc[rt][2] + bias.z;
                r.w = acc[rt][3] + bias.w;
                if (ct == 3) {
                    // s2 -> out f32 [N][10]; only cols 0..9 exist
                    if (g < 2) {
                        *(float4*)(out + (size_t)row * 10 + c0) = r;
                    } else if (g == 2) {
                        out[(size_t)row * 10 + 8] = r.x;
                        out[(size_t)row * 10 + 9] = r.y;
                    }
                } else {
                    __half* p = ct == 0 ? q2h + (size_t)row * 16 + c0
                              : kv2h + (size_t)row * 32 + (ct == 2 ? 16 : 0) + c0;
                    __half2 h01 = __floats2half2_rn(r.x, r.y);
                    __half2 h23 = __floats2half2_rn(r.z, r.w);
                    uint2 u;
                    u.x = *(unsigned*)&h01;
                    u.y = *(unsigned*)&h23;
                    *(uint2*)p = u;
                }
            }
        }
    }
}

// ---------- layer-2 fused attention: 8 lanes/dst, half2 loads, zero predication ----
// q2h/kv2h channels 10..15 are exact zeros -> 8-lane shfl dot is exact; pad lanes
// accumulate zeros. 32 dsts per 256-thread block; per-edge loads halved.
__global__ __launch_bounds__(256) void node_attn2(
    const __half* __restrict__ q2h, const __half* __restrict__ kv2h,
    const int* __restrict__ rowptr, const int* __restrict__ esrc,
    float* __restrict__ out)  // pre-loaded with skip (h @ Ws2 + bs2)
{
    const int t = threadIdx.x;
    const int d = blockIdx.x * 32 + (t >> 3);
    if (d >= NN) return;
    const int c = t & 7;  // channel pair (2c, 2c+1)
    const int beg = rowptr[d];
    const int end = rowptr[d + 1];

    float2 qv = __half22float2(*(const __half2*)(q2h + (size_t)d * 16 + 2 * c));
    qv.x *= 0.31622776601683794f;  // fold 1/sqrt(10)
    qv.y *= 0.31622776601683794f;

    float2 accA = make_float2(0.f, 0.f), accB = make_float2(0.f, 0.f);
    float sA = 0.f, sB = 0.f;

    int i = beg;
    int sa = (i < end) ? esrc[i] : 0;
    int sb = (i + 1 < end) ? esrc[i + 1] : 0;
    __half2 kA = *(const __half2*)(kv2h + (size_t)sa * 32 + 2 * c);
    __half2 vA = *(const __half2*)(kv2h + (size_t)sa * 32 + 16 + 2 * c);
    __half2 kB = *(const __half2*)(kv2h + (size_t)sb * 32 + 2 * c);
    __half2 vB = *(const __half2*)(kv2h + (size_t)sb * 32 + 16 + 2 * c);

    while (i + 1 < end) {
        const int ni = i + 2;
        const int nsa = (ni < end) ? esrc[ni] : 0;
        const int nsb = (ni + 1 < end) ? esrc[ni + 1] : 0;
        const __half2 nkA = *(const __half2*)(kv2h + (size_t)nsa * 32 + 2 * c);
        const __half2 nvA = *(const __half2*)(kv2h + (size_t)nsa * 32 + 16 + 2 * c);
        const __half2 nkB = *(const __half2*)(kv2h + (size_t)nsb * 32 + 2 * c);
        const __half2 nvB = *(const __half2*)(kv2h + (size_t)nsb * 32 + 16 + 2 * c);

        const float2 kAf = __half22float2(kA);
        const float2 kBf = __half22float2(kB);
        const float2 vAf = __half22float2(vA);
        const float2 vBf = __half22float2(vB);

        float pA = qv.x * kAf.x + qv.y * kAf.y;
        float pB = qv.x * kBf.x + qv.y * kBf.y;
        pA += __shfl_xor(pA, 4, 8); pB += __shfl_xor(pB, 4, 8);
        pA += __shfl_xor(pA, 2, 8); pB += __shfl_xor(pB, 2, 8);
        pA += __shfl_xor(pA, 1, 8); pB += __shfl_xor(pB, 1, 8);

        const float exA = __expf(pA - 2.0f);
        accA.x += exA * vAf.x;
        accA.y += exA * vAf.y;
        sA += exA;

        const float exB = __expf(pB - 2.0f);
        accB.x += exB * vBf.x;
        accB.y += exB * vBf.y;
        sB += exB;

        kA = nkA; vA = nvA; kB = nkB; vB = nvB;
        i = ni;
    }
    if (i < end) {
        const float2 kAf = __half22float2(kA);
        const float2 vAf = __half22float2(vA);
        float pA = qv.x * kAf.x + qv.y * kAf.y;
        pA += __shfl_xor(pA, 4, 8);
        pA += __shfl_xor(pA, 2, 8);
        pA += __shfl_xor(pA, 1, 8);
        const float exA = __expf(pA - 2.0f);
        accA.x += exA * vAf.x;
        accA.y += exA * vAf.y;
        sA += exA;
    }

    if (c < 5) {  // channels 2c, 2c+1 in 0..9
        const float inv = 1.f / (sA + sB + 1e-16f);
        float2 o = *(float2*)(out + (size_t)d * 10 + 2 * c);
        o.x += (accA.x + accB.x) * inv;
        o.y += (accA.y + accB.y) * inv;
        *(float2*)(out + (size_t)d * 10 + 2 * c) = o;
    }
}

extern "C" void kernel_launch(void* const* d_in, const int* in_sizes, int n_in,
                              void* d_out, int out_size, void* d_ws, size_t ws_size,
                              hipStream_t stream) {
    const float* x   = (const float*)d_in[0];
    const int*   ei  = (const int*)d_in[1];
    const float* Wq1 = (const float*)d_in[2];  const float* bq1 = (const float*)d_in[3];
    const float* Wk1 = (const float*)d_in[4];  const float* bk1 = (const float*)d_in[5];
    const float* Wv1 = (const float*)d_in[6];  const float* bv1 = (const float*)d_in[7];
    const float* Ws1 = (const float*)d_in[8];  const float* bs1 = (const float*)d_in[9];
    const float* Wq2 = (const float*)d_in[10]; const float* bq2 = (const float*)d_in[11];
    const float* Wk2 = (const float*)d_in[12]; const float* bk2 = (const float*)d_in[13];
    const float* Wv2 = (const float*)d_in[14]; const float* bv2 = (const float*)d_in[15];
    const float* Ws2 = (const float*)d_in[16]; const float* bs2 = (const float*)d_in[17];
    float* out = (float*)d_out;

    const int* src = ei;
    const int* dst = ei + EE;

    // workspace carve
    __half* q1h   = (__half*)d_ws;                      // N*128 f16
    __half* k1h   = q1h + (size_t)NN * 128;             // N*128 f16
    __half* v1h   = k1h + (size_t)NN * 128;             // N*128 f16
    __half* skiph = v1h + (size_t)NN * 128;             // N*128 f16 (x @ Ws + bs)
    __half* hb    = skiph + (size_t)NN * 128;           // N*128 f16 (h)
    __half* Wt    = hb + (size_t)NN * 128;              // 4*128*128 f16
    __half* W2t   = Wt + 4 * 128 * 128;                 // 64*128 f16
    __half* q2h   = W2t + 64 * 128;                     // N*16 f16 (padded)
    __half* kv2h  = q2h + (size_t)NN * 16;              // N*32 f16 (k|v packed, 64B/node)
    float* bias2  = (float*)(kv2h + (size_t)NN * 32);   // 64 f32
    int* deg      = (int*)(bias2 + 64);                 // N
    int* rowptr   = deg + NN;                           // N+1
    int* cursor   = rowptr + NN + 1;                    // N
    int* bsum     = cursor + NN;                        // NB
    int* esrc     = bsum + NB;                          // E (src sorted by dst)

    // prep + CSR build
    hipMemsetAsync(deg, 0, (size_t)NN * sizeof(int), stream);
    deg_count<<<EE / 256, 256, 0, stream>>>(dst, deg);
    build_weights<<<64, 256, 0, stream>>>(Wq1, Wk1, Wv1, Ws1,
                                          Wq2, bq2, Wk2, bk2, Wv2, bv2, Ws2, bs2,
                                          Wt, W2t, bias2);
    block_sums<<<NB, 256, 0, stream>>>(deg, bsum);
    scan_bsums<<<1, 256, 0, stream>>>(bsum);
    write_rowptr<<<NB, 256, 0, stream>>>(deg, bsum, rowptr, cursor);
    scatter_edges<<<EE / 256, 256, 0, stream>>>(src, dst, cursor, esrc);

    // layer 1 projections via MFMA (2 mats/block, 64-row waves, LDS-staged stores)
    gemm_l1_mfma<<<dim3((NN + 127) / 128, 2), 128, 0, stream>>>(
        x, Wt, bq1, bk1, bv1, bs1, q1h, k1h, v1h, skiph);

    // fused layer-1 attention + skip + ELU -> h fp16
    node_attn1<<<NN / 4, 256, 0, stream>>>(q1h, k1h, v1h, rowptr, esrc, skiph, hb);

    // layer-2 projections via MFMA (s2 written directly to d_out)
    node_l2_mfma<<<(NN + 127) / 128, 128, 0, stream>>>(hb, W2t, bias2, q2h, kv2h, out);

    // fused layer-2 attention (8 lanes/dst, half2)
    node_attn2<<<(NN + 31) / 32, 256, 0, stream>>>(q2h, kv2h, rowptr, esrc, out);
}

// Round 17
// 216.147 us; speedup vs baseline: 1.0786x; 1.0075x over previous
//
#include <hip/hip_runtime.h>
#include <hip/hip_fp16.h>
#include <math.h>

#define NN 50000
#define EE 800000
#define NB 196  // ceil(NN/256)
// IN_DIM = 128, HEADS*HIDDEN = 128, NUM_CLASSES = 10

typedef _Float16 f16x8 __attribute__((ext_vector_type(8)));
typedef float f32x4 __attribute__((ext_vector_type(4)));

__device__ inline float elu1(float x) { return x > 0.f ? x : expm1f(x); }

// ---------- prep: x (f32) -> xh (f16), dst-degree histogram hidden under the stream ----------
__global__ __launch_bounds__(256) void convert_x_deg(
    const float* __restrict__ x, __half* __restrict__ xh,
    const int* __restrict__ dst, int* __restrict__ deg)
{
    const int i = blockIdx.x * 256 + threadIdx.x;  // float4 index
    if (i < NN * 32) {
        const float4 v = ((const float4*)x)[i];
        ((__half2*)xh)[i * 2] = __floats2half2_rn(v.x, v.y);
        ((__half2*)xh)[i * 2 + 1] = __floats2half2_rn(v.z, v.w);
    }
    if (i < EE) atomicAdd(&deg[dst[i]], 1);
}

// ---------- prep: W1 transpose (f16) + W2 pack (f16, zero-padded) in one kernel ----------
__global__ __launch_bounds__(256) void build_weights(
    const float* __restrict__ Wq, const float* __restrict__ Wk,
    const float* __restrict__ Wv, const float* __restrict__ Ws,
    const float* __restrict__ Wq2, const float* __restrict__ bq2,
    const float* __restrict__ Wk2, const float* __restrict__ bk2,
    const float* __restrict__ Wv2, const float* __restrict__ bv2,
    const float* __restrict__ Ws2, const float* __restrict__ bs2,
    __half* __restrict__ Wt, __half* __restrict__ W2t, float* __restrict__ bias2)
{
    // part A (blocks 0..31): W2[128][10] x4 -> W2t[64][128] zero-padded + bias2[64]
    const int idx = blockIdx.x * 256 + threadIdx.x;
    if (idx < 8192) {
        const int col = idx >> 7, k = idx & 127;
        const int m = col >> 4, j = col & 15;
        const float* W = m == 0 ? Wq2 : m == 1 ? Wk2 : m == 2 ? Wv2 : Ws2;
        W2t[idx] = (__half)(j < 10 ? W[k * 10 + j] : 0.f);
    }
    if (idx < 64) {
        const int m = idx >> 4, j = idx & 15;
        const float* b = m == 0 ? bq2 : m == 1 ? bk2 : m == 2 ? bv2 : bs2;
        bias2[idx] = j < 10 ? b[j] : 0.f;
    }
    // part B (all 64 blocks): W1[k][c] -> Wt[mat][c][k] f16 via LDS tile transpose
    __shared__ float tile[32][33];
    const int mat = blockIdx.x >> 4;
    const int tid = blockIdx.x & 15;
    const int k0 = (tid >> 2) * 32, c0 = (tid & 3) * 32;
    const float* W = mat == 0 ? Wq : mat == 1 ? Wk : mat == 2 ? Wv : Ws;
    const int r = threadIdx.x >> 5;   // 0..7
    const int c = threadIdx.x & 31;
    for (int rr = r; rr < 32; rr += 8) tile[rr][c] = W[(size_t)(k0 + rr) * 128 + c0 + c];
    __syncthreads();
    for (int rr = r; rr < 32; rr += 8)
        Wt[((size_t)mat * 128 + c0 + rr) * 128 + k0 + c] = (__half)tile[c][rr];
}

// ---------- CSR build: multi-block scan, scatter ----------
__global__ __launch_bounds__(256) void block_sums(
    const int* __restrict__ deg, int* __restrict__ bsum)
{
    __shared__ int ws[4];
    const int t = threadIdx.x;
    const int idx = blockIdx.x * 256 + t;
    int d = (idx < NN) ? deg[idx] : 0;
    #pragma unroll
    for (int off = 32; off; off >>= 1) d += __shfl_down(d, off, 64);
    if ((t & 63) == 0) ws[t >> 6] = d;
    __syncthreads();
    if (t == 0) bsum[blockIdx.x] = ws[0] + ws[1] + ws[2] + ws[3];
}

__global__ __launch_bounds__(256) void scan_bsums(int* __restrict__ bsum)
{
    __shared__ int s[256];
    const int t = threadIdx.x;
    int v = (t < NB) ? bsum[t] : 0;
    s[t] = v;
    __syncthreads();
    for (int off = 1; off < 256; off <<= 1) {
        int u = (t >= off) ? s[t - off] : 0;
        __syncthreads();
        s[t] += u;
        __syncthreads();
    }
    if (t < NB) bsum[t] = (t == 0) ? 0 : s[t - 1];
}

__global__ __launch_bounds__(256) void write_rowptr(
    const int* __restrict__ deg, const int* __restrict__ bsum,
    int* __restrict__ rowptr, int* __restrict__ cursor)
{
    __shared__ int s[256];
    const int t = threadIdx.x;
    const int idx = blockIdx.x * 256 + t;
    const int d = (idx < NN) ? deg[idx] : 0;
    s[t] = d;
    __syncthreads();
    for (int off = 1; off < 256; off <<= 1) {
        int u = (t >= off) ? s[t - off] : 0;
        __syncthreads();
        s[t] += u;
        __syncthreads();
    }
    const int excl = ((t == 0) ? 0 : s[t - 1]) + bsum[blockIdx.x];
    if (idx < NN) {
        rowptr[idx] = excl;
        cursor[idx] = excl;
    }
    if (idx == NN - 1) rowptr[NN] = excl + d;  // == EE
}

__global__ __launch_bounds__(256) void scatter_edges(
    const int* __restrict__ src, const int* __restrict__ dst,
    int* __restrict__ cursor, int* __restrict__ esrc)
{
    const int e = blockIdx.x * 256 + threadIdx.x;
    if (e >= EE) return;
    const int d = dst[e];
    const int pos = atomicAdd(&cursor[d], 1);
    esrc[pos] = src[e];
}

// ---------- layer-1 projections via MFMA: 2 mats per block, 64-row waves ----------
// Reads xh fp16 (single f16x8 fragment loads). Output staged in padded LDS
// ([128][136] halfs) then stored as FULL 256B rows — no partial-line write
// amplification. Histogram NOT fused (R13/R15: costs 15-20us inside MFMA kernel).
__global__ __launch_bounds__(128) void gemm_l1_mfma(
    const __half* __restrict__ xh, const __half* __restrict__ Wt,
    const float* __restrict__ bq, const float* __restrict__ bk,
    const float* __restrict__ bv, const float* __restrict__ bs,
    __half* __restrict__ oqh, __half* __restrict__ okh,
    __half* __restrict__ ovh, __half* __restrict__ osh)
{
    __shared__ __half lds[128 * 136];  // 34 KB, row stride 272B (16-aligned)
    const int pair = blockIdx.y;  // 0: mats {0,1}; 1: mats {2,3}
    const int t = threadIdx.x;
    const int wave = t >> 6;
    const int lane = t & 63;
    const int l = lane & 15;
    const int g = lane >> 4;  // 0..3
    const int brow0 = blockIdx.x * 128;
    const int wrow0 = brow0 + wave * 64;

    // x fragments (B operand): fp16 direct; lane&15 = row-in-tile
    f16x8 xf[4][4];
    #pragma unroll
    for (int rt = 0; rt < 4; ++rt) {
        int arow = wrow0 + rt * 16 + l;
        if (arow >= NN) arow = NN - 1;  // clamp: garbage rows never stored
        #pragma unroll
        for (int kk = 0; kk < 4; ++kk)
            xf[rt][kk] = *(const f16x8*)((const _Float16*)xh + (size_t)arow * 128 + kk * 32 + g * 8);
    }

    for (int mi = 0; mi < 2; ++mi) {
        const int mat = pair * 2 + mi;
        const float* b = mat == 0 ? bq : mat == 1 ? bk : mat == 2 ? bv : bs;
        __half* o = mat == 0 ? oqh : mat == 1 ? okh : mat == 2 ? ovh : osh;
        const _Float16* wt = (const _Float16*)Wt + (size_t)mat * 128 * 128;

        f16x8 wf[4], wfn[4];
        #pragma unroll
        for (int kk = 0; kk < 4; ++kk)
            wf[kk] = *(const f16x8*)(wt + (size_t)l * 128 + kk * 32 + g * 8);

        for (int ct = 0; ct < 8; ++ct) {
            if (ct < 7) {
                const int ncol = (ct + 1) * 16 + l;
                #pragma unroll
                for (int kk = 0; kk < 4; ++kk)
                    wfn[kk] = *(const f16x8*)(wt + (size_t)ncol * 128 + kk * 32 + g * 8);
            }
            f32x4 acc[4];
            #pragma unroll
            for (int rt = 0; rt < 4; ++rt) acc[rt] = (f32x4){0.f, 0.f, 0.f, 0.f};
            #pragma unroll
            for (int kk = 0; kk < 4; ++kk)
                #pragma unroll
                for (int rt = 0; rt < 4; ++rt)
                    acc[rt] = __builtin_amdgcn_mfma_f32_16x16x32_f16(wf[kk], xf[rt][kk], acc[rt], 0, 0, 0);

            const int col0 = ct * 16 + g * 4;
            const float4 bias = *(const float4*)(b + col0);
            #pragma unroll
            for (int rt = 0; rt < 4; ++rt) {
                __half2 h01 = __floats2half2_rn(acc[rt][0] + bias.x, acc[rt][1] + bias.y);
                __half2 h23 = __floats2half2_rn(acc[rt][2] + bias.z, acc[rt][3] + bias.w);
                uint2 u;
                u.x = *(unsigned*)&h01;
                u.y = *(unsigned*)&h23;
                *(uint2*)&lds[(wave * 64 + rt * 16 + l) * 136 + col0] = u;
            }
            #pragma unroll
            for (int kk = 0; kk < 4; ++kk) wf[kk] = wfn[kk];
        }

        __syncthreads();
        // cooperative full-row store: idx = 16B unit; 16 lanes cover one full 256B row
        #pragma unroll
        for (int i = 0; i < 16; ++i) {
            const int idx = i * 128 + t;   // 0..2047
            const int row = idx >> 4;
            const int seg = idx & 15;
            const int grow = brow0 + row;
            if (grow < NN)
                *(uint4*)(o + (size_t)grow * 128 + seg * 8) = *(const uint4*)&lds[row * 136 + seg * 8];
        }
        __syncthreads();
    }
}

// ---------- layer-1 fused attention + skip + ELU -> h (fp16) ----------
// static-shift softmax (shift-invariant; logits ~ N(0,1) so exp(lg-4) is safe).
__global__ __launch_bounds__(256) void node_attn1(
    const __half* __restrict__ q1, const __half* __restrict__ k1,
    const __half* __restrict__ v1,
    const int* __restrict__ rowptr, const int* __restrict__ esrc,
    const __half* __restrict__ skiph,  // x @ Ws + bs (f16)
    __half* __restrict__ hb)           // out: h = elu(skip + attn), fp16
{
    const int t = threadIdx.x;
    const int wid = __builtin_amdgcn_readfirstlane(t >> 6);
    const int d = blockIdx.x * 4 + wid;
    if (d >= NN) return;
    const int lane = t & 63;
    const int ch2 = lane << 1;

    const int beg = rowptr[d];
    const int end = rowptr[d + 1];

    float2 qv = __half22float2(*(const __half2*)(q1 + (size_t)d * 128 + ch2));
    qv.x *= 0.17677669529663687f;  // fold 1/sqrt(32) into q
    qv.y *= 0.17677669529663687f;

    float2 accA = make_float2(0.f, 0.f), accB = make_float2(0.f, 0.f);
    float sA = 0.f, sB = 0.f;

    int i = beg;
    int sa = (i < end) ? esrc[i] : 0;
    int sb = (i + 1 < end) ? esrc[i + 1] : 0;
    __half2 kA = *(const __half2*)(k1 + (size_t)sa * 128 + ch2);
    __half2 vA = *(const __half2*)(v1 + (size_t)sa * 128 + ch2);
    __half2 kB = *(const __half2*)(k1 + (size_t)sb * 128 + ch2);
    __half2 vB = *(const __half2*)(v1 + (size_t)sb * 128 + ch2);

    while (i + 1 < end) {
        const int ni = i + 2;
        const int nsa = (ni < end) ? esrc[ni] : 0;
        const int nsb = (ni + 1 < end) ? esrc[ni + 1] : 0;
        const __half2 nkA = *(const __half2*)(k1 + (size_t)nsa * 128 + ch2);
        const __half2 nvA = *(const __half2*)(v1 + (size_t)nsa * 128 + ch2);
        const __half2 nkB = *(const __half2*)(k1 + (size_t)nsb * 128 + ch2);
        const __half2 nvB = *(const __half2*)(v1 + (size_t)nsb * 128 + ch2);

        const float2 kAf = __half22float2(kA);
        const float2 kBf = __half22float2(kB);
        const float2 vAf = __half22float2(vA);
        const float2 vBf = __half22float2(vB);

        float pA = qv.x * kAf.x + qv.y * kAf.y;
        float pB = qv.x * kBf.x + qv.y * kBf.y;
        pA += __shfl_xor(pA, 8, 16); pB += __shfl_xor(pB, 8, 16);
        pA += __shfl_xor(pA, 4, 16); pB += __shfl_xor(pB, 4, 16);
        pA += __shfl_xor(pA, 2, 16); pB += __shfl_xor(pB, 2, 16);
        pA += __shfl_xor(pA, 1, 16); pB += __shfl_xor(pB, 1, 16);

        const float exA = __expf(pA - 4.0f);
        accA.x += exA * vAf.x;
        accA.y += exA * vAf.y;
        sA += exA;

        const float exB = __expf(pB - 4.0f);
        accB.x += exB * vBf.x;
        accB.y += exB * vBf.y;
        sB += exB;

        kA = nkA; vA = nvA; kB = nkB; vB = nvB;
        i = ni;
    }
    if (i < end) {  // odd tail -> chain A
        const float2 kAf = __half22float2(kA);
        const float2 vAf = __half22float2(vA);
        float pA = qv.x * kAf.x + qv.y * kAf.y;
        pA += __shfl_xor(pA, 8, 16);
        pA += __shfl_xor(pA, 4, 16);
        pA += __shfl_xor(pA, 2, 16);
        pA += __shfl_xor(pA, 1, 16);
        const float exA = __expf(pA - 4.0f);
        accA.x += exA * vAf.x;
        accA.y += exA * vAf.y;
        sA += exA;
    }

    const float inv = 1.f / (sA + sB + 1e-16f);
    float2 o = __half22float2(*(const __half2*)(skiph + (size_t)d * 128 + ch2));
    o.x = elu1(o.x + (accA.x + accB.x) * inv);
    o.y = elu1(o.y + (accA.y + accB.y) * inv);
    *(__half2*)(hb + (size_t)d * 128 + ch2) = __floats2half2_rn(o.x, o.y);
}

// ---------- layer-2 projections via MFMA: h[N,128] @ W2t^T + bias2 ----------
// ct tile = matrix: 0->q2h[N][16], 1->k half of kv2h, 2->v half, 3->s2 (f32 out).
__global__ __launch_bounds__(128) void node_l2_mfma(
    const __half* __restrict__ hb, const __half* __restrict__ W2t,
    const float* __restrict__ bias2,
    __half* __restrict__ q2h, __half* __restrict__ kv2h,
    float* __restrict__ out)
{
    const int t = threadIdx.x;
    const int wave = t >> 6;
    const int lane = t & 63;
    const int l = lane & 15;
    const int g = lane >> 4;  // 0..3
    const int wrow0 = blockIdx.x * 128 + wave * 64;
    if (wrow0 >= NN) return;
    const bool full = (wrow0 + 64 <= NN);

    f16x8 hf[4][4];
    #pragma unroll
    for (int rt = 0; rt < 4; ++rt) {
        int arow = wrow0 + rt * 16 + l;
        if (!full && arow >= NN) arow = NN - 1;
        #pragma unroll
        for (int kk = 0; kk < 4; ++kk)
            hf[rt][kk] = *(const f16x8*)((const _Float16*)hb + (size_t)arow * 128 + kk * 32 + g * 8);
    }

    #pragma unroll
    for (int ct = 0; ct < 4; ++ct) {
        const int col = ct * 16 + l;
        f16x8 wf[4];
        #pragma unroll
        for (int kk = 0; kk < 4; ++kk)
            wf[kk] = *(const f16x8*)((const _Float16*)W2t + (size_t)col * 128 + kk * 32 + g * 8);

        f32x4 acc[4];
        #pragma unroll
        for (int rt = 0; rt < 4; ++rt) acc[rt] = (f32x4){0.f, 0.f, 0.f, 0.f};
        #pragma unroll
        for (int kk = 0; kk < 4; ++kk)
            #pragma unroll
            for (int rt = 0; rt < 4; ++rt)
                acc[rt] = __builtin_amdgcn_mfma_f32_16x16x32_f16(wf[kk], hf[rt][kk], acc[rt], 0, 0, 0);

        const int c0 = g * 4;  // within-tile column base
        const float4 bias = *(const float4*)(bias2 + ct * 16 + c0);
        #pragma unroll
        for (int rt = 0; rt < 4; ++rt) {
            const int row = wrow0 + rt * 16 + l;
            if (full || row < NN) {
                float4 r;
                r.x = acc[rt][0] + bias.x;
                r.y = acc[rt][1] + bias.y;
                r.z = acc[rt][2] + bias.z;
                r.w = acc[rt][3] + bias.w;
                if (ct == 3) {
                    // s2 -> out f32 [N][10]; only cols 0..9 exist
                    if (g < 2) {
                        *(float4*)(out + (size_t)row * 10 + c0) = r;
                    } else if (g == 2) {
                        out[(size_t)row * 10 + 8] = r.x;
                        out[(size_t)row * 10 + 9] = r.y;
                    }
                } else {
                    __half* p = ct == 0 ? q2h + (size_t)row * 16 + c0
                              : kv2h + (size_t)row * 32 + (ct == 2 ? 16 : 0) + c0;
                    __half2 h01 = __floats2half2_rn(r.x, r.y);
                    __half2 h23 = __floats2half2_rn(r.z, r.w);
                    uint2 u;
                    u.x = *(unsigned*)&h01;
                    u.y = *(unsigned*)&h23;
                    *(uint2*)p = u;
                }
            }
        }
    }
}

// ---------- layer-2 fused attention: 8 lanes/dst, 4 chains, half2 loads ----------
// kv2 working set (3.2MB) is L2-resident -> latency/issue-bound; 4 independent
// online chains keep 8 loads in flight per group. Pad channels are exact zeros.
__global__ __launch_bounds__(256) void node_attn2(
    const __half* __restrict__ q2h, const __half* __restrict__ kv2h,
    const int* __restrict__ rowptr, const int* __restrict__ esrc,
    float* __restrict__ out)  // pre-loaded with skip (h @ Ws2 + bs2)
{
    const int t = threadIdx.x;
    const int d = blockIdx.x * 32 + (t >> 3);
    if (d >= NN) return;
    const int c = t & 7;  // channel pair (2c, 2c+1)
    const int beg = rowptr[d];
    const int end = rowptr[d + 1];

    float2 qv = __half22float2(*(const __half2*)(q2h + (size_t)d * 16 + 2 * c));
    qv.x *= 0.31622776601683794f;  // fold 1/sqrt(10)
    qv.y *= 0.31622776601683794f;

    float2 acc[4];
    float ss[4];
    #pragma unroll
    for (int j = 0; j < 4; ++j) { acc[j] = make_float2(0.f, 0.f); ss[j] = 0.f; }

    int i = beg;
    __half2 kr[4], vr[4];
    #pragma unroll
    for (int j = 0; j < 4; ++j) {
        const int s = (i + j < end) ? esrc[i + j] : 0;
        kr[j] = *(const __half2*)(kv2h + (size_t)s * 32 + 2 * c);
        vr[j] = *(const __half2*)(kv2h + (size_t)s * 32 + 16 + 2 * c);
    }

    while (i + 3 < end) {
        const int ni = i + 4;
        __half2 nk[4], nv[4];
        #pragma unroll
        for (int j = 0; j < 4; ++j) {
            const int s = (ni + j < end) ? esrc[ni + j] : 0;
            nk[j] = *(const __half2*)(kv2h + (size_t)s * 32 + 2 * c);
            nv[j] = *(const __half2*)(kv2h + (size_t)s * 32 + 16 + 2 * c);
        }
        #pragma unroll
        for (int j = 0; j < 4; ++j) {
            const float2 kf = __half22float2(kr[j]);
            const float2 vf = __half22float2(vr[j]);
            float p = qv.x * kf.x + qv.y * kf.y;
            p += __shfl_xor(p, 4, 8);
            p += __shfl_xor(p, 2, 8);
            p += __shfl_xor(p, 1, 8);
            const float ex = __expf(p - 2.0f);
            acc[j].x += ex * vf.x;
            acc[j].y += ex * vf.y;
            ss[j] += ex;
        }
        #pragma unroll
        for (int j = 0; j < 4; ++j) { kr[j] = nk[j]; vr[j] = nv[j]; }
        i = ni;
    }
    // tail (0..3 edges): direct loads, chain 0
    for (; i < end; ++i) {
        const int s = esrc[i];
        const float2 kf = __half22float2(*(const __half2*)(kv2h + (size_t)s * 32 + 2 * c));
        const float2 vf = __half22float2(*(const __half2*)(kv2h + (size_t)s * 32 + 16 + 2 * c));
        float p = qv.x * kf.x + qv.y * kf.y;
        p += __shfl_xor(p, 4, 8);
        p += __shfl_xor(p, 2, 8);
        p += __shfl_xor(p, 1, 8);
        const float ex = __expf(p - 2.0f);
        acc[0].x += ex * vf.x;
        acc[0].y += ex * vf.y;
        ss[0] += ex;
    }

    if (c < 5) {  // channels 2c, 2c+1 in 0..9
        const float ssum = ss[0] + ss[1] + ss[2] + ss[3];
        const float inv = 1.f / (ssum + 1e-16f);
        float2 o = *(float2*)(out + (size_t)d * 10 + 2 * c);
        o.x += (acc[0].x + acc[1].x + acc[2].x + acc[3].x) * inv;
        o.y += (acc[0].y + acc[1].y + acc[2].y + acc[3].y) * inv;
        *(float2*)(out + (size_t)d * 10 + 2 * c) = o;
    }
}

extern "C" void kernel_launch(void* const* d_in, const int* in_sizes, int n_in,
                              void* d_out, int out_size, void* d_ws, size_t ws_size,
                              hipStream_t stream) {
    const float* x   = (const float*)d_in[0];
    const int*   ei  = (const int*)d_in[1];
    const float* Wq1 = (const float*)d_in[2];  const float* bq1 = (const float*)d_in[3];
    const float* Wk1 = (const float*)d_in[4];  const float* bk1 = (const float*)d_in[5];
    const float* Wv1 = (const float*)d_in[6];  const float* bv1 = (const float*)d_in[7];
    const float* Ws1 = (const float*)d_in[8];  const float* bs1 = (const float*)d_in[9];
    const float* Wq2 = (const float*)d_in[10]; const float* bq2 = (const float*)d_in[11];
    const float* Wk2 = (const float*)d_in[12]; const float* bk2 = (const float*)d_in[13];
    const float* Wv2 = (const float*)d_in[14]; const float* bv2 = (const float*)d_in[15];
    const float* Ws2 = (const float*)d_in[16]; const float* bs2 = (const float*)d_in[17];
    float* out = (float*)d_out;

    const int* src = ei;
    const int* dst = ei + EE;

    // workspace carve
    __half* xh    = (__half*)d_ws;                      // N*128 f16 (x)
    __half* q1h   = xh + (size_t)NN * 128;              // N*128 f16
    __half* k1h   = q1h + (size_t)NN * 128;             // N*128 f16
    __half* v1h   = k1h + (size_t)NN * 128;             // N*128 f16
    __half* skiph = v1h + (size_t)NN * 128;             // N*128 f16 (x @ Ws + bs)
    __half* hb    = skiph + (size_t)NN * 128;           // N*128 f16 (h)
    __half* Wt    = hb + (size_t)NN * 128;              // 4*128*128 f16
    __half* W2t   = Wt + 4 * 128 * 128;                 // 64*128 f16
    __half* q2h   = W2t + 64 * 128;                     // N*16 f16 (padded)
    __half* kv2h  = q2h + (size_t)NN * 16;              // N*32 f16 (k|v packed, 64B/node)
    float* bias2  = (float*)(kv2h + (size_t)NN * 32);   // 64 f32
    int* deg      = (int*)(bias2 + 64);                 // N
    int* rowptr   = deg + NN;                           // N+1
    int* cursor   = rowptr + NN + 1;                    // N
    int* bsum     = cursor + NN;                        // NB
    int* esrc     = bsum + NB;                          // E (src sorted by dst)

    // prep: streaming x->f16 with hidden histogram; weight repacks
    hipMemsetAsync(deg, 0, (size_t)NN * sizeof(int), stream);
    convert_x_deg<<<(NN * 32 + 255) / 256, 256, 0, stream>>>(x, xh, dst, deg);
    build_weights<<<64, 256, 0, stream>>>(Wq1, Wk1, Wv1, Ws1,
                                          Wq2, bq2, Wk2, bk2, Wv2, bv2, Ws2, bs2,
                                          Wt, W2t, bias2);

    // CSR build (reused by both layers)
    block_sums<<<NB, 256, 0, stream>>>(deg, bsum);
    scan_bsums<<<1, 256, 0, stream>>>(bsum);
    write_rowptr<<<NB, 256, 0, stream>>>(deg, bsum, rowptr, cursor);
    scatter_edges<<<EE / 256, 256, 0, stream>>>(src, dst, cursor, esrc);

    // layer 1 projections via MFMA (2 mats/block, fp16 x, LDS-staged stores)
    gemm_l1_mfma<<<dim3((NN + 127) / 128, 2), 128, 0, stream>>>(
        xh, Wt, bq1, bk1, bv1, bs1, q1h, k1h, v1h, skiph);

    // fused layer-1 attention + skip + ELU -> h fp16
    node_attn1<<<NN / 4, 256, 0, stream>>>(q1h, k1h, v1h, rowptr, esrc, skiph, hb);

    // layer-2 projections via MFMA (s2 written directly to d_out)
    node_l2_mfma<<<(NN + 127) / 128, 128, 0, stream>>>(hb, W2t, bias2, q2h, kv2h, out);

    // fused layer-2 attention (8 lanes/dst, 4 chains)
    node_attn2<<<(NN + 31) / 32, 256, 0, stream>>>(q2h, kv2h, rowptr, esrc, out);
}

// Round 18
// 207.018 us; speedup vs baseline: 1.1262x; 1.0441x over previous
//
#include <hip/hip_runtime.h>
#include <hip/hip_fp16.h>
#include <math.h>

#define NN 50000
#define EE 800000
#define NB 196  // ceil(NN/256)
// IN_DIM = 128, HEADS*HIDDEN = 128, NUM_CLASSES = 10

typedef _Float16 f16x8 __attribute__((ext_vector_type(8)));
typedef float f32x4 __attribute__((ext_vector_type(4)));
typedef float f32x2 __attribute__((ext_vector_type(2)));

__device__ inline float elu1(float x) { return x > 0.f ? x : expm1f(x); }

// ---------- prep: x (f32) -> xh (f16), dst-degree histogram hidden under the stream ----------
__global__ __launch_bounds__(256) void convert_x_deg(
    const float* __restrict__ x, __half* __restrict__ xh,
    const int* __restrict__ dst, int* __restrict__ deg)
{
    const int i = blockIdx.x * 256 + threadIdx.x;  // float4 index
    if (i < NN * 32) {
        const float4 v = ((const float4*)x)[i];
        ((__half2*)xh)[i * 2] = __floats2half2_rn(v.x, v.y);
        ((__half2*)xh)[i * 2 + 1] = __floats2half2_rn(v.z, v.w);
    }
    if (i < EE) atomicAdd(&deg[dst[i]], 1);
}

// ---------- prep: W1 transpose (f16) + W2 pack (f16, zero-padded) in one kernel ----------
__global__ __launch_bounds__(256) void build_weights(
    const float* __restrict__ Wq, const float* __restrict__ Wk,
    const float* __restrict__ Wv, const float* __restrict__ Ws,
    const float* __restrict__ Wq2, const float* __restrict__ bq2,
    const float* __restrict__ Wk2, const float* __restrict__ bk2,
    const float* __restrict__ Wv2, const float* __restrict__ bv2,
    const float* __restrict__ Ws2, const float* __restrict__ bs2,
    __half* __restrict__ Wt, __half* __restrict__ W2t, float* __restrict__ bias2)
{
    // part A (blocks 0..31): W2[128][10] x4 -> W2t[64][128] zero-padded + bias2[64]
    const int idx = blockIdx.x * 256 + threadIdx.x;
    if (idx < 8192) {
        const int col = idx >> 7, k = idx & 127;
        const int m = col >> 4, j = col & 15;
        const float* W = m == 0 ? Wq2 : m == 1 ? Wk2 : m == 2 ? Wv2 : Ws2;
        W2t[idx] = (__half)(j < 10 ? W[k * 10 + j] : 0.f);
    }
    if (idx < 64) {
        const int m = idx >> 4, j = idx & 15;
        const float* b = m == 0 ? bq2 : m == 1 ? bk2 : m == 2 ? bv2 : bs2;
        bias2[idx] = j < 10 ? b[j] : 0.f;
    }
    // part B (all 64 blocks): W1[k][c] -> Wt[mat][c][k] f16 via LDS tile transpose
    __shared__ float tile[32][33];
    const int mat = blockIdx.x >> 4;
    const int tid = blockIdx.x & 15;
    const int k0 = (tid >> 2) * 32, c0 = (tid & 3) * 32;
    const float* W = mat == 0 ? Wq : mat == 1 ? Wk : mat == 2 ? Wv : Ws;
    const int r = threadIdx.x >> 5;   // 0..7
    const int c = threadIdx.x & 31;
    for (int rr = r; rr < 32; rr += 8) tile[rr][c] = W[(size_t)(k0 + rr) * 128 + c0 + c];
    __syncthreads();
    for (int rr = r; rr < 32; rr += 8)
        Wt[((size_t)mat * 128 + c0 + rr) * 128 + k0 + c] = (__half)tile[c][rr];
}

// ---------- CSR build: multi-block scan, scatter ----------
__global__ __launch_bounds__(256) void block_sums(
    const int* __restrict__ deg, int* __restrict__ bsum)
{
    __shared__ int ws[4];
    const int t = threadIdx.x;
    const int idx = blockIdx.x * 256 + t;
    int d = (idx < NN) ? deg[idx] : 0;
    #pragma unroll
    for (int off = 32; off; off >>= 1) d += __shfl_down(d, off, 64);
    if ((t & 63) == 0) ws[t >> 6] = d;
    __syncthreads();
    if (t == 0) bsum[blockIdx.x] = ws[0] + ws[1] + ws[2] + ws[3];
}

__global__ __launch_bounds__(256) void scan_bsums(int* __restrict__ bsum)
{
    __shared__ int s[256];
    const int t = threadIdx.x;
    int v = (t < NB) ? bsum[t] : 0;
    s[t] = v;
    __syncthreads();
    for (int off = 1; off < 256; off <<= 1) {
        int u = (t >= off) ? s[t - off] : 0;
        __syncthreads();
        s[t] += u;
        __syncthreads();
    }
    if (t < NB) bsum[t] = (t == 0) ? 0 : s[t - 1];
}

__global__ __launch_bounds__(256) void write_rowptr(
    const int* __restrict__ deg, const int* __restrict__ bsum,
    int* __restrict__ rowptr, int* __restrict__ cursor)
{
    __shared__ int s[256];
    const int t = threadIdx.x;
    const int idx = blockIdx.x * 256 + t;
    const int d = (idx < NN) ? deg[idx] : 0;
    s[t] = d;
    __syncthreads();
    for (int off = 1; off < 256; off <<= 1) {
        int u = (t >= off) ? s[t - off] : 0;
        __syncthreads();
        s[t] += u;
        __syncthreads();
    }
    const int excl = ((t == 0) ? 0 : s[t - 1]) + bsum[blockIdx.x];
    if (idx < NN) {
        rowptr[idx] = excl;
        cursor[idx] = excl;
    }
    if (idx == NN - 1) rowptr[NN] = excl + d;  // == EE
}

__global__ __launch_bounds__(256) void scatter_edges(
    const int* __restrict__ src, const int* __restrict__ dst,
    int* __restrict__ cursor, int* __restrict__ esrc)
{
    const int e = blockIdx.x * 256 + threadIdx.x;
    if (e >= EE) return;
    const int d = dst[e];
    const int pos = atomicAdd(&cursor[d], 1);
    esrc[pos] = src[e];
}

// ---------- layer-1 projections via MFMA: 2 mats per block, 64-row waves ----------
// q/skip stay f16; k/v stored as fp8 e4m3 (halves attn1's per-XCD L2-fill working
// set, the proven 59us floor). All outputs LDS-staged, stored as full lines.
__global__ __launch_bounds__(128) void gemm_l1_mfma(
    const __half* __restrict__ xh, const __half* __restrict__ Wt,
    const float* __restrict__ bq, const float* __restrict__ bk,
    const float* __restrict__ bv, const float* __restrict__ bs,
    __half* __restrict__ oqh, unsigned char* __restrict__ ok8,
    unsigned char* __restrict__ ov8, __half* __restrict__ osh)
{
    __shared__ __align__(16) unsigned char ldsraw[128 * 272];  // 34 KB
    const int pair = blockIdx.y;  // 0: mats {0(q f16),1(k fp8)}; 1: mats {2(v fp8),3(s f16)}
    const int t = threadIdx.x;
    const int wave = t >> 6;
    const int lane = t & 63;
    const int l = lane & 15;
    const int g = lane >> 4;  // 0..3
    const int brow0 = blockIdx.x * 128;
    const int wrow0 = brow0 + wave * 64;

    // x fragments (B operand): fp16 direct; lane&15 = row-in-tile
    f16x8 xf[4][4];
    #pragma unroll
    for (int rt = 0; rt < 4; ++rt) {
        int arow = wrow0 + rt * 16 + l;
        if (arow >= NN) arow = NN - 1;  // clamp: garbage rows never stored
        #pragma unroll
        for (int kk = 0; kk < 4; ++kk)
            xf[rt][kk] = *(const f16x8*)((const _Float16*)xh + (size_t)arow * 128 + kk * 32 + g * 8);
    }

    for (int mi = 0; mi < 2; ++mi) {
        const int mat = pair * 2 + mi;
        const bool isfp8 = (mat == 1 || mat == 2);
        const float* b = mat == 0 ? bq : mat == 1 ? bk : mat == 2 ? bv : bs;
        const _Float16* wt = (const _Float16*)Wt + (size_t)mat * 128 * 128;

        f16x8 wf[4], wfn[4];
        #pragma unroll
        for (int kk = 0; kk < 4; ++kk)
            wf[kk] = *(const f16x8*)(wt + (size_t)l * 128 + kk * 32 + g * 8);

        for (int ct = 0; ct < 8; ++ct) {
            if (ct < 7) {
                const int ncol = (ct + 1) * 16 + l;
                #pragma unroll
                for (int kk = 0; kk < 4; ++kk)
                    wfn[kk] = *(const f16x8*)(wt + (size_t)ncol * 128 + kk * 32 + g * 8);
            }
            f32x4 acc[4];
            #pragma unroll
            for (int rt = 0; rt < 4; ++rt) acc[rt] = (f32x4){0.f, 0.f, 0.f, 0.f};
            #pragma unroll
            for (int kk = 0; kk < 4; ++kk)
                #pragma unroll
                for (int rt = 0; rt < 4; ++rt)
                    acc[rt] = __builtin_amdgcn_mfma_f32_16x16x32_f16(wf[kk], xf[rt][kk], acc[rt], 0, 0, 0);

            const int col0 = ct * 16 + g * 4;
            const float4 bias = *(const float4*)(b + col0);
            #pragma unroll
            for (int rt = 0; rt < 4; ++rt) {
                const int lrow = wave * 64 + rt * 16 + l;
                const float r0 = acc[rt][0] + bias.x;
                const float r1 = acc[rt][1] + bias.y;
                const float r2 = acc[rt][2] + bias.z;
                const float r3 = acc[rt][3] + bias.w;
                if (isfp8) {
                    int p = __builtin_amdgcn_cvt_pk_fp8_f32(r0, r1, 0, false);
                    p = __builtin_amdgcn_cvt_pk_fp8_f32(r2, r3, p, true);
                    *(int*)&ldsraw[lrow * 144 + col0] = p;       // 144B row stride
                } else {
                    __half2 h01 = __floats2half2_rn(r0, r1);
                    __half2 h23 = __floats2half2_rn(r2, r3);
                    uint2 u;
                    u.x = *(unsigned*)&h01;
                    u.y = *(unsigned*)&h23;
                    *(uint2*)&ldsraw[lrow * 272 + col0 * 2] = u; // 272B row stride
                }
            }
            #pragma unroll
            for (int kk = 0; kk < 4; ++kk) wf[kk] = wfn[kk];
        }

        __syncthreads();
        if (isfp8) {
            unsigned char* o = (mat == 1) ? ok8 : ov8;
            // 128 rows x 128B; 16B units: 8/row, 1024 total, 8 iters
            #pragma unroll
            for (int i = 0; i < 8; ++i) {
                const int idx = i * 128 + t;
                const int row = idx >> 3;
                const int seg = idx & 7;
                const int grow = brow0 + row;
                if (grow < NN)
                    *(uint4*)(o + (size_t)grow * 128 + seg * 16) = *(const uint4*)&ldsraw[row * 144 + seg * 16];
            }
        } else {
            __half* o = (mat == 0) ? oqh : osh;
            // 128 rows x 256B; 16B units: 16/row, 2048 total, 16 iters
            #pragma unroll
            for (int i = 0; i < 16; ++i) {
                const int idx = i * 128 + t;
                const int row = idx >> 4;
                const int seg = idx & 15;
                const int grow = brow0 + row;
                if (grow < NN)
                    *(uint4*)(o + (size_t)grow * 128 + seg * 8) = *(const uint4*)&ldsraw[row * 272 + seg * 16];
            }
        }
        __syncthreads();
    }
}

// ---------- layer-1 fused attention + skip + ELU -> h (fp16) ----------
// k/v gathered as fp8 e4m3 (2 bytes/lane), decoded with native cvt_pk_f32_fp8.
// static-shift softmax (shift-invariant; logits ~ N(0,1) so exp(lg-4) is safe).
__global__ __launch_bounds__(256) void node_attn1(
    const __half* __restrict__ q1, const unsigned char* __restrict__ k8,
    const unsigned char* __restrict__ v8,
    const int* __restrict__ rowptr, const int* __restrict__ esrc,
    const __half* __restrict__ skiph,  // x @ Ws + bs (f16)
    __half* __restrict__ hb)           // out: h = elu(skip + attn), fp16
{
    const int t = threadIdx.x;
    const int wid = __builtin_amdgcn_readfirstlane(t >> 6);
    const int d = blockIdx.x * 4 + wid;
    if (d >= NN) return;
    const int lane = t & 63;
    const int ch2 = lane << 1;

    const int beg = rowptr[d];
    const int end = rowptr[d + 1];

    float2 qv = __half22float2(*(const __half2*)(q1 + (size_t)d * 128 + ch2));
    qv.x *= 0.17677669529663687f;  // fold 1/sqrt(32) into q
    qv.y *= 0.17677669529663687f;

    float2 accA = make_float2(0.f, 0.f), accB = make_float2(0.f, 0.f);
    float sA = 0.f, sB = 0.f;

    int i = beg;
    int sa = (i < end) ? esrc[i] : 0;
    int sb = (i + 1 < end) ? esrc[i + 1] : 0;
    unsigned kA = *(const unsigned short*)(k8 + (size_t)sa * 128 + ch2);
    unsigned vA = *(const unsigned short*)(v8 + (size_t)sa * 128 + ch2);
    unsigned kB = *(const unsigned short*)(k8 + (size_t)sb * 128 + ch2);
    unsigned vB = *(const unsigned short*)(v8 + (size_t)sb * 128 + ch2);

    while (i + 1 < end) {
        const int ni = i + 2;
        const int nsa = (ni < end) ? esrc[ni] : 0;
        const int nsb = (ni + 1 < end) ? esrc[ni + 1] : 0;
        const unsigned nkA = *(const unsigned short*)(k8 + (size_t)nsa * 128 + ch2);
        const unsigned nvA = *(const unsigned short*)(v8 + (size_t)nsa * 128 + ch2);
        const unsigned nkB = *(const unsigned short*)(k8 + (size_t)nsb * 128 + ch2);
        const unsigned nvB = *(const unsigned short*)(v8 + (size_t)nsb * 128 + ch2);

        const f32x2 kAf = __builtin_amdgcn_cvt_pk_f32_fp8((int)kA, false);
        const f32x2 kBf = __builtin_amdgcn_cvt_pk_f32_fp8((int)kB, false);
        const f32x2 vAf = __builtin_amdgcn_cvt_pk_f32_fp8((int)vA, false);
        const f32x2 vBf = __builtin_amdgcn_cvt_pk_f32_fp8((int)vB, false);

        float pA = qv.x * kAf[0] + qv.y * kAf[1];
        float pB = qv.x * kBf[0] + qv.y * kBf[1];
        pA += __shfl_xor(pA, 8, 16); pB += __shfl_xor(pB, 8, 16);
        pA += __shfl_xor(pA, 4, 16); pB += __shfl_xor(pB, 4, 16);
        pA += __shfl_xor(pA, 2, 16); pB += __shfl_xor(pB, 2, 16);
        pA += __shfl_xor(pA, 1, 16); pB += __shfl_xor(pB, 1, 16);

        const float exA = __expf(pA - 4.0f);
        accA.x += exA * vAf[0];
        accA.y += exA * vAf[1];
        sA += exA;

        const float exB = __expf(pB - 4.0f);
        accB.x += exB * vBf[0];
        accB.y += exB * vBf[1];
        sB += exB;

        kA = nkA; vA = nvA; kB = nkB; vB = nvB;
        i = ni;
    }
    if (i < end) {  // odd tail -> chain A
        const f32x2 kAf = __builtin_amdgcn_cvt_pk_f32_fp8((int)kA, false);
        const f32x2 vAf = __builtin_amdgcn_cvt_pk_f32_fp8((int)vA, false);
        float pA = qv.x * kAf[0] + qv.y * kAf[1];
        pA += __shfl_xor(pA, 8, 16);
        pA += __shfl_xor(pA, 4, 16);
        pA += __shfl_xor(pA, 2, 16);
        pA += __shfl_xor(pA, 1, 16);
        const float exA = __expf(pA - 4.0f);
        accA.x += exA * vAf[0];
        accA.y += exA * vAf[1];
        sA += exA;
    }

    const float inv = 1.f / (sA + sB + 1e-16f);
    float2 o = __half22float2(*(const __half2*)(skiph + (size_t)d * 128 + ch2));
    o.x = elu1(o.x + (accA.x + accB.x) * inv);
    o.y = elu1(o.y + (accA.y + accB.y) * inv);
    *(__half2*)(hb + (size_t)d * 128 + ch2) = __floats2half2_rn(o.x, o.y);
}

// ---------- layer-2 projections via MFMA: h[N,128] @ W2t^T + bias2 ----------
// ct tile = matrix: 0->q2h[N][16], 1->k half of kv2h, 2->v half, 3->s2 (f32 out).
__global__ __launch_bounds__(128) void node_l2_mfma(
    const __half* __restrict__ hb, const __half* __restrict__ W2t,
    const float* __restrict__ bias2,
    __half* __restrict__ q2h, __half* __restrict__ kv2h,
    float* __restrict__ out)
{
    const int t = threadIdx.x;
    const int wave = t >> 6;
    const int lane = t & 63;
    const int l = lane & 15;
    const int g = lane >> 4;  // 0..3
    const int wrow0 = blockIdx.x * 128 + wave * 64;
    if (wrow0 >= NN) return;
    const bool full = (wrow0 + 64 <= NN);

    f16x8 hf[4][4];
    #pragma unroll
    for (int rt = 0; rt < 4; ++rt) {
        int arow = wrow0 + rt * 16 + l;
        if (!full && arow >= NN) arow = NN - 1;
        #pragma unroll
        for (int kk = 0; kk < 4; ++kk)
            hf[rt][kk] = *(const f16x8*)((const _Float16*)hb + (size_t)arow * 128 + kk * 32 + g * 8);
    }

    #pragma unroll
    for (int ct = 0; ct < 4; ++ct) {
        const int col = ct * 16 + l;
        f16x8 wf[4];
        #pragma unroll
        for (int kk = 0; kk < 4; ++kk)
            wf[kk] = *(const f16x8*)((const _Float16*)W2t + (size_t)col * 128 + kk * 32 + g * 8);

        f32x4 acc[4];
        #pragma unroll
        for (int rt = 0; rt < 4; ++rt) acc[rt] = (f32x4){0.f, 0.f, 0.f, 0.f};
        #pragma unroll
        for (int kk = 0; kk < 4; ++kk)
            #pragma unroll
            for (int rt = 0; rt < 4; ++rt)
                acc[rt] = __builtin_amdgcn_mfma_f32_16x16x32_f16(wf[kk], hf[rt][kk], acc[rt], 0, 0, 0);

        const int c0 = g * 4;  // within-tile column base
        const float4 bias = *(const float4*)(bias2 + ct * 16 + c0);
        #pragma unroll
        for (int rt = 0; rt < 4; ++rt) {
            const int row = wrow0 + rt * 16 + l;
            if (full || row < NN) {
                float4 r;
                r.x = acc[rt][0] + bias.x;
                r.y = acc[rt][1] + bias.y;
                r.z = acc[rt][2] + bias.z;
                r.w = acc[rt][3] + bias.w;
                if (ct == 3) {
                    // s2 -> out f32 [N][10]; only cols 0..9 exist
                    if (g < 2) {
                        *(float4*)(out + (size_t)row * 10 + c0) = r;
                    } else if (g == 2) {
                        out[(size_t)row * 10 + 8] = r.x;
                        out[(size_t)row * 10 + 9] = r.y;
                    }
                } else {
                    __half* p = ct == 0 ? q2h + (size_t)row * 16 + c0
                              : kv2h + (size_t)row * 32 + (ct == 2 ? 16 : 0) + c0;
                    __half2 h01 = __floats2half2_rn(r.x, r.y);
                    __half2 h23 = __floats2half2_rn(r.z, r.w);
                    uint2 u;
                    u.x = *(unsigned*)&h01;
                    u.y = *(unsigned*)&h23;
                    *(uint2*)p = u;
                }
            }
        }
    }
}

// ---------- layer-2 fused attention: 8 lanes/dst, 4 chains, half2 loads ----------
__global__ __launch_bounds__(256) void node_attn2(
    const __half* __restrict__ q2h, const __half* __restrict__ kv2h,
    const int* __restrict__ rowptr, const int* __restrict__ esrc,
    float* __restrict__ out)  // pre-loaded with skip (h @ Ws2 + bs2)
{
    const int t = threadIdx.x;
    const int d = blockIdx.x * 32 + (t >> 3);
    if (d >= NN) return;
    const int c = t & 7;  // channel pair (2c, 2c+1)
    const int beg = rowptr[d];
    const int end = rowptr[d + 1];

    float2 qv = __half22float2(*(const __half2*)(q2h + (size_t)d * 16 + 2 * c));
    qv.x *= 0.31622776601683794f;  // fold 1/sqrt(10)
    qv.y *= 0.31622776601683794f;

    float2 acc[4];
    float ss[4];
    #pragma unroll
    for (int j = 0; j < 4; ++j) { acc[j] = make_float2(0.f, 0.f); ss[j] = 0.f; }

    int i = beg;
    __half2 kr[4], vr[4];
    #pragma unroll
    for (int j = 0; j < 4; ++j) {
        const int s = (i + j < end) ? esrc[i + j] : 0;
        kr[j] = *(const __half2*)(kv2h + (size_t)s * 32 + 2 * c);
        vr[j] = *(const __half2*)(kv2h + (size_t)s * 32 + 16 + 2 * c);
    }

    while (i + 3 < end) {
        const int ni = i + 4;
        __half2 nk[4], nv[4];
        #pragma unroll
        for (int j = 0; j < 4; ++j) {
            const int s = (ni + j < end) ? esrc[ni + j] : 0;
            nk[j] = *(const __half2*)(kv2h + (size_t)s * 32 + 2 * c);
            nv[j] = *(const __half2*)(kv2h + (size_t)s * 32 + 16 + 2 * c);
        }
        #pragma unroll
        for (int j = 0; j < 4; ++j) {
            const float2 kf = __half22float2(kr[j]);
            const float2 vf = __half22float2(vr[j]);
            float p = qv.x * kf.x + qv.y * kf.y;
            p += __shfl_xor(p, 4, 8);
            p += __shfl_xor(p, 2, 8);
            p += __shfl_xor(p, 1, 8);
            const float ex = __expf(p - 2.0f);
            acc[j].x += ex * vf.x;
            acc[j].y += ex * vf.y;
            ss[j] += ex;
        }
        #pragma unroll
        for (int j = 0; j < 4; ++j) { kr[j] = nk[j]; vr[j] = nv[j]; }
        i = ni;
    }
    // tail (0..3 edges): direct loads, chain 0
    for (; i < end; ++i) {
        const int s = esrc[i];
        const float2 kf = __half22float2(*(const __half2*)(kv2h + (size_t)s * 32 + 2 * c));
        const float2 vf = __half22float2(*(const __half2*)(kv2h + (size_t)s * 32 + 16 + 2 * c));
        float p = qv.x * kf.x + qv.y * kf.y;
        p += __shfl_xor(p, 4, 8);
        p += __shfl_xor(p, 2, 8);
        p += __shfl_xor(p, 1, 8);
        const float ex = __expf(p - 2.0f);
        acc[0].x += ex * vf.x;
        acc[0].y += ex * vf.y;
        ss[0] += ex;
    }

    if (c < 5) {  // channels 2c, 2c+1 in 0..9
        const float ssum = ss[0] + ss[1] + ss[2] + ss[3];
        const float inv = 1.f / (ssum + 1e-16f);
        float2 o = *(float2*)(out + (size_t)d * 10 + 2 * c);
        o.x += (acc[0].x + acc[1].x + acc[2].x + acc[3].x) * inv;
        o.y += (acc[0].y + acc[1].y + acc[2].y + acc[3].y) * inv;
        *(float2*)(out + (size_t)d * 10 + 2 * c) = o;
    }
}

extern "C" void kernel_launch(void* const* d_in, const int* in_sizes, int n_in,
                              void* d_out, int out_size, void* d_ws, size_t ws_size,
                              hipStream_t stream) {
    const float* x   = (const float*)d_in[0];
    const int*   ei  = (const int*)d_in[1];
    const float* Wq1 = (const float*)d_in[2];  const float* bq1 = (const float*)d_in[3];
    const float* Wk1 = (const float*)d_in[4];  const float* bk1 = (const float*)d_in[5];
    const float* Wv1 = (const float*)d_in[6];  const float* bv1 = (const float*)d_in[7];
    const float* Ws1 = (const float*)d_in[8];  const float* bs1 = (const float*)d_in[9];
    const float* Wq2 = (const float*)d_in[10]; const float* bq2 = (const float*)d_in[11];
    const float* Wk2 = (const float*)d_in[12]; const float* bk2 = (const float*)d_in[13];
    const float* Wv2 = (const float*)d_in[14]; const float* bv2 = (const float*)d_in[15];
    const float* Ws2 = (const float*)d_in[16]; const float* bs2 = (const float*)d_in[17];
    float* out = (float*)d_out;

    const int* src = ei;
    const int* dst = ei + EE;

    // workspace carve
    __half* xh    = (__half*)d_ws;                      // N*128 f16 (x)
    __half* q1h   = xh + (size_t)NN * 128;              // N*128 f16
    __half* skiph = q1h + (size_t)NN * 128;             // N*128 f16 (x @ Ws + bs)
    __half* hb    = skiph + (size_t)NN * 128;           // N*128 f16 (h)
    unsigned char* k8 = (unsigned char*)(hb + (size_t)NN * 128);  // N*128 fp8
    unsigned char* v8 = k8 + (size_t)NN * 128;          // N*128 fp8
    __half* Wt    = (__half*)(v8 + (size_t)NN * 128);   // 4*128*128 f16
    __half* W2t   = Wt + 4 * 128 * 128;                 // 64*128 f16
    __half* q2h   = W2t + 64 * 128;                     // N*16 f16 (padded)
    __half* kv2h  = q2h + (size_t)NN * 16;              // N*32 f16 (k|v packed, 64B/node)
    float* bias2  = (float*)(kv2h + (size_t)NN * 32);   // 64 f32
    int* deg      = (int*)(bias2 + 64);                 // N
    int* rowptr   = deg + NN;                           // N+1
    int* cursor   = rowptr + NN + 1;                    // N
    int* bsum     = cursor + NN;                        // NB
    int* esrc     = bsum + NB;                          // E (src sorted by dst)

    // prep: streaming x->f16 with hidden histogram; weight repacks
    hipMemsetAsync(deg, 0, (size_t)NN * sizeof(int), stream);
    convert_x_deg<<<(NN * 32 + 255) / 256, 256, 0, stream>>>(x, xh, dst, deg);
    build_weights<<<64, 256, 0, stream>>>(Wq1, Wk1, Wv1, Ws1,
                                          Wq2, bq2, Wk2, bk2, Wv2, bv2, Ws2, bs2,
                                          Wt, W2t, bias2);

    // CSR build (reused by both layers)
    block_sums<<<NB, 256, 0, stream>>>(deg, bsum);
    scan_bsums<<<1, 256, 0, stream>>>(bsum);
    write_rowptr<<<NB, 256, 0, stream>>>(deg, bsum, rowptr, cursor);
    scatter_edges<<<EE / 256, 256, 0, stream>>>(src, dst, cursor, esrc);

    // layer 1 projections via MFMA (q/skip f16, k/v fp8, LDS-staged stores)
    gemm_l1_mfma<<<dim3((NN + 127) / 128, 2), 128, 0, stream>>>(
        xh, Wt, bq1, bk1, bv1, bs1, q1h, k8, v8, skiph);

    // fused layer-1 attention + skip + ELU -> h fp16 (fp8 k/v gather)
    node_attn1<<<NN / 4, 256, 0, stream>>>(q1h, k8, v8, rowptr, esrc, skiph, hb);

    // layer-2 projections via MFMA (s2 written directly to d_out)
    node_l2_mfma<<<(NN + 127) / 128, 128, 0, stream>>>(hb, W2t, bias2, q2h, kv2h, out);

    // fused layer-2 attention (8 lanes/dst, 4 chains)
    node_attn2<<<(NN + 31) / 32, 256, 0, stream>>>(q2h, kv2h, rowptr, esrc, out);
}

// Round 19
// 191.177 us; speedup vs baseline: 1.2195x; 1.0829x over previous
//
#include <hip/hip_runtime.h>
#include <hip/hip_fp16.h>
#include <math.h>

#define NN 50000
#define EE 800000
#define NB 196   // ceil(NN/256)
#define NBK 128  // dst-range buckets
#define BKN 391  // nodes per bucket (128*391 = 50048 >= NN)
#define CH 4096  // edges per bucket_stage block
// IN_DIM = 128, HEADS*HIDDEN = 128, NUM_CLASSES = 10

typedef _Float16 f16x8 __attribute__((ext_vector_type(8)));
typedef float f32x4 __attribute__((ext_vector_type(4)));
typedef float f32x2 __attribute__((ext_vector_type(2)));

__device__ inline float elu1(float x) { return x > 0.f ? x : expm1f(x); }

// ---------- prep: x (f32) -> xh (f16), dst-degree histogram hidden under the stream ----------
__global__ __launch_bounds__(256) void convert_x_deg(
    const float* __restrict__ x, __half* __restrict__ xh,
    const int* __restrict__ dst, int* __restrict__ deg)
{
    const int i = blockIdx.x * 256 + threadIdx.x;  // float4 index
    if (i < NN * 32) {
        const float4 v = ((const float4*)x)[i];
        ((__half2*)xh)[i * 2] = __floats2half2_rn(v.x, v.y);
        ((__half2*)xh)[i * 2 + 1] = __floats2half2_rn(v.z, v.w);
    }
    if (i < EE) atomicAdd(&deg[dst[i]], 1);
}

// ---------- prep: W1 transpose (f16) + W2 pack (f16, zero-padded) in one kernel ----------
__global__ __launch_bounds__(256) void build_weights(
    const float* __restrict__ Wq, const float* __restrict__ Wk,
    const float* __restrict__ Wv, const float* __restrict__ Ws,
    const float* __restrict__ Wq2, const float* __restrict__ bq2,
    const float* __restrict__ Wk2, const float* __restrict__ bk2,
    const float* __restrict__ Wv2, const float* __restrict__ bv2,
    const float* __restrict__ Ws2, const float* __restrict__ bs2,
    __half* __restrict__ Wt, __half* __restrict__ W2t, float* __restrict__ bias2)
{
    const int idx = blockIdx.x * 256 + threadIdx.x;
    if (idx < 8192) {
        const int col = idx >> 7, k = idx & 127;
        const int m = col >> 4, j = col & 15;
        const float* W = m == 0 ? Wq2 : m == 1 ? Wk2 : m == 2 ? Wv2 : Ws2;
        W2t[idx] = (__half)(j < 10 ? W[k * 10 + j] : 0.f);
    }
    if (idx < 64) {
        const int m = idx >> 4, j = idx & 15;
        const float* b = m == 0 ? bq2 : m == 1 ? bk2 : m == 2 ? bv2 : bs2;
        bias2[idx] = j < 10 ? b[j] : 0.f;
    }
    __shared__ float tile[32][33];
    const int mat = blockIdx.x >> 4;
    const int tid = blockIdx.x & 15;
    const int k0 = (tid >> 2) * 32, c0 = (tid & 3) * 32;
    const float* W = mat == 0 ? Wq : mat == 1 ? Wk : mat == 2 ? Wv : Ws;
    const int r = threadIdx.x >> 5;   // 0..7
    const int c = threadIdx.x & 31;
    for (int rr = r; rr < 32; rr += 8) tile[rr][c] = W[(size_t)(k0 + rr) * 128 + c0 + c];
    __syncthreads();
    for (int rr = r; rr < 32; rr += 8)
        Wt[((size_t)mat * 128 + c0 + rr) * 128 + k0 + c] = (__half)tile[c][rr];
}

// ---------- CSR build: multi-block scan ----------
__global__ __launch_bounds__(256) void block_sums(
    const int* __restrict__ deg, int* __restrict__ bsum)
{
    __shared__ int ws[4];
    const int t = threadIdx.x;
    const int idx = blockIdx.x * 256 + t;
    int d = (idx < NN) ? deg[idx] : 0;
    #pragma unroll
    for (int off = 32; off; off >>= 1) d += __shfl_down(d, off, 64);
    if ((t & 63) == 0) ws[t >> 6] = d;
    __syncthreads();
    if (t == 0) bsum[blockIdx.x] = ws[0] + ws[1] + ws[2] + ws[3];
}

__global__ __launch_bounds__(256) void scan_bsums(int* __restrict__ bsum)
{
    __shared__ int s[256];
    const int t = threadIdx.x;
    int v = (t < NB) ? bsum[t] : 0;
    s[t] = v;
    __syncthreads();
    for (int off = 1; off < 256; off <<= 1) {
        int u = (t >= off) ? s[t - off] : 0;
        __syncthreads();
        s[t] += u;
        __syncthreads();
    }
    if (t < NB) bsum[t] = (t == 0) ? 0 : s[t - 1];
}

// rowptr + bucket cursors (bcur[b] = rowptr[b*BKN], bucket base in esrc/bpair)
__global__ __launch_bounds__(256) void write_rowptr(
    const int* __restrict__ deg, const int* __restrict__ bsum,
    int* __restrict__ rowptr, int* __restrict__ bcur)
{
    __shared__ int s[256];
    const int t = threadIdx.x;
    const int idx = blockIdx.x * 256 + t;
    const int d = (idx < NN) ? deg[idx] : 0;
    s[t] = d;
    __syncthreads();
    for (int off = 1; off < 256; off <<= 1) {
        int u = (t >= off) ? s[t - off] : 0;
        __syncthreads();
        s[t] += u;
        __syncthreads();
    }
    const int excl = ((t == 0) ? 0 : s[t - 1]) + bsum[blockIdx.x];
    if (idx < NN) {
        rowptr[idx] = excl;
        if (idx % BKN == 0) bcur[idx / BKN] = excl;
    }
    if (idx == NN - 1) rowptr[NN] = excl + d;  // == EE
}

// ---------- pass 1: bucket edges by dst range; LDS-sorted chunks, bulk-reserved
// contiguous copy-out -> bpair writes are (near-)full lines.
__global__ __launch_bounds__(256) void bucket_stage(
    const int* __restrict__ src, const int* __restrict__ dst,
    int* __restrict__ bcur, unsigned* __restrict__ bpair)
{
    __shared__ unsigned ep[CH];        // packed (dst<<16)|src
    __shared__ unsigned short eb[CH];  // bucket id
    __shared__ unsigned stg[CH];       // bucket-sorted
    __shared__ int cnt[NBK], off[NBK], pos[NBK], gbase[NBK];
    const int t = threadIdx.x;
    const int e0 = blockIdx.x * CH;
    const int n = min(CH, EE - e0);
    if (t < NBK) cnt[t] = 0;
    __syncthreads();
    for (int i = t; i < n; i += 256) {
        const int s = src[e0 + i], d = dst[e0 + i];
        ep[i] = (unsigned)s | ((unsigned)d << 16);
        const int b = d / BKN;
        eb[i] = (unsigned short)b;
        atomicAdd(&cnt[b], 1);
    }
    __syncthreads();
    if (t == 0) {
        int run = 0;
        for (int b = 0; b < NBK; ++b) { off[b] = run; pos[b] = run; run += cnt[b]; }
    }
    __syncthreads();
    if (t < NBK && cnt[t] > 0) gbase[t] = atomicAdd(&bcur[t], cnt[t]);
    __syncthreads();
    for (int i = t; i < n; i += 256) {
        const int b = eb[i];
        const int p = atomicAdd(&pos[b], 1);
        stg[p] = ep[i];
    }
    __syncthreads();
    for (int i = t; i < n; i += 256) {
        // largest b with off[b] <= i (empty buckets skipped by 'largest')
        int lo = 0, hi = NBK - 1;
        while (lo < hi) { const int mid = (lo + hi + 1) >> 1; if (off[mid] <= i) lo = mid; else hi = mid - 1; }
        bpair[gbase[lo] + (i - off[lo])] = stg[i];
    }
}

// ---------- pass 2: one block per bucket; LDS cursors; esrc range exclusive to
// this block -> lines assembled in one L2, written once.
__global__ __launch_bounds__(256) void bucket_scatter(
    const unsigned* __restrict__ bpair, const int* __restrict__ rowptr,
    int* __restrict__ esrc)
{
    __shared__ int lcur[BKN];
    const int b = blockIdx.x;
    const int n0 = b * BKN;
    const int n1 = min(NN, n0 + BKN);
    const int nn = n1 - n0;
    const int t = threadIdx.x;
    for (int i = t; i < nn; i += 256) lcur[i] = rowptr[n0 + i];
    __syncthreads();
    const int ebeg = rowptr[n0];
    const int eend = rowptr[n1];
    for (int i = ebeg + t; i < eend; i += 256) {
        const unsigned p = bpair[i];
        const int s = (int)(p & 0xFFFFu);
        const int d = (int)(p >> 16);
        const int pos = atomicAdd(&lcur[d - n0], 1);
        esrc[pos] = s;
    }
}

// ---------- layer-1 projections via MFMA: 2 mats per block, 64-row waves ----------
// q/skip f16; k/v fp8 e4m3 (halved attn1 working set). LDS-staged full-line stores.
__global__ __launch_bounds__(128) void gemm_l1_mfma(
    const __half* __restrict__ xh, const __half* __restrict__ Wt,
    const float* __restrict__ bq, const float* __restrict__ bk,
    const float* __restrict__ bv, const float* __restrict__ bs,
    __half* __restrict__ oqh, unsigned char* __restrict__ ok8,
    unsigned char* __restrict__ ov8, __half* __restrict__ osh)
{
    __shared__ __align__(16) unsigned char ldsraw[128 * 272];  // 34 KB
    const int pair = blockIdx.y;  // 0: mats {0(q f16),1(k fp8)}; 1: mats {2(v fp8),3(s f16)}
    const int t = threadIdx.x;
    const int wave = t >> 6;
    const int lane = t & 63;
    const int l = lane & 15;
    const int g = lane >> 4;  // 0..3
    const int brow0 = blockIdx.x * 128;
    const int wrow0 = brow0 + wave * 64;

    f16x8 xf[4][4];
    #pragma unroll
    for (int rt = 0; rt < 4; ++rt) {
        int arow = wrow0 + rt * 16 + l;
        if (arow >= NN) arow = NN - 1;  // clamp: garbage rows never stored
        #pragma unroll
        for (int kk = 0; kk < 4; ++kk)
            xf[rt][kk] = *(const f16x8*)((const _Float16*)xh + (size_t)arow * 128 + kk * 32 + g * 8);
    }

    for (int mi = 0; mi < 2; ++mi) {
        const int mat = pair * 2 + mi;
        const bool isfp8 = (mat == 1 || mat == 2);
        const float* b = mat == 0 ? bq : mat == 1 ? bk : mat == 2 ? bv : bs;
        const _Float16* wt = (const _Float16*)Wt + (size_t)mat * 128 * 128;

        f16x8 wf[4], wfn[4];
        #pragma unroll
        for (int kk = 0; kk < 4; ++kk)
            wf[kk] = *(const f16x8*)(wt + (size_t)l * 128 + kk * 32 + g * 8);

        for (int ct = 0; ct < 8; ++ct) {
            if (ct < 7) {
                const int ncol = (ct + 1) * 16 + l;
                #pragma unroll
                for (int kk = 0; kk < 4; ++kk)
                    wfn[kk] = *(const f16x8*)(wt + (size_t)ncol * 128 + kk * 32 + g * 8);
            }
            f32x4 acc[4];
            #pragma unroll
            for (int rt = 0; rt < 4; ++rt) acc[rt] = (f32x4){0.f, 0.f, 0.f, 0.f};
            #pragma unroll
            for (int kk = 0; kk < 4; ++kk)
                #pragma unroll
                for (int rt = 0; rt < 4; ++rt)
                    acc[rt] = __builtin_amdgcn_mfma_f32_16x16x32_f16(wf[kk], xf[rt][kk], acc[rt], 0, 0, 0);

            const int col0 = ct * 16 + g * 4;
            const float4 bias = *(const float4*)(b + col0);
            #pragma unroll
            for (int rt = 0; rt < 4; ++rt) {
                const int lrow = wave * 64 + rt * 16 + l;
                const float r0 = acc[rt][0] + bias.x;
                const float r1 = acc[rt][1] + bias.y;
                const float r2 = acc[rt][2] + bias.z;
                const float r3 = acc[rt][3] + bias.w;
                if (isfp8) {
                    int p = __builtin_amdgcn_cvt_pk_fp8_f32(r0, r1, 0, false);
                    p = __builtin_amdgcn_cvt_pk_fp8_f32(r2, r3, p, true);
                    *(int*)&ldsraw[lrow * 144 + col0] = p;       // 144B row stride
                } else {
                    __half2 h01 = __floats2half2_rn(r0, r1);
                    __half2 h23 = __floats2half2_rn(r2, r3);
                    uint2 u;
                    u.x = *(unsigned*)&h01;
                    u.y = *(unsigned*)&h23;
                    *(uint2*)&ldsraw[lrow * 272 + col0 * 2] = u; // 272B row stride
                }
            }
            #pragma unroll
            for (int kk = 0; kk < 4; ++kk) wf[kk] = wfn[kk];
        }

        __syncthreads();
        if (isfp8) {
            unsigned char* o = (mat == 1) ? ok8 : ov8;
            #pragma unroll
            for (int i = 0; i < 8; ++i) {
                const int idx = i * 128 + t;
                const int row = idx >> 3;
                const int seg = idx & 7;
                const int grow = brow0 + row;
                if (grow < NN)
                    *(uint4*)(o + (size_t)grow * 128 + seg * 16) = *(const uint4*)&ldsraw[row * 144 + seg * 16];
            }
        } else {
            __half* o = (mat == 0) ? oqh : osh;
            #pragma unroll
            for (int i = 0; i < 16; ++i) {
                const int idx = i * 128 + t;
                const int row = idx >> 4;
                const int seg = idx & 15;
                const int grow = brow0 + row;
                if (grow < NN)
                    *(uint4*)(o + (size_t)grow * 128 + seg * 8) = *(const uint4*)&ldsraw[row * 272 + seg * 16];
            }
        }
        __syncthreads();
    }
}

// ---------- layer-1 fused attention + skip + ELU -> h (fp16) ----------
// k/v gathered as fp8 e4m3, decoded with native cvt_pk_f32_fp8.
__global__ __launch_bounds__(256) void node_attn1(
    const __half* __restrict__ q1, const unsigned char* __restrict__ k8,
    const unsigned char* __restrict__ v8,
    const int* __restrict__ rowptr, const int* __restrict__ esrc,
    const __half* __restrict__ skiph,  // x @ Ws + bs (f16)
    __half* __restrict__ hb)           // out: h = elu(skip + attn), fp16
{
    const int t = threadIdx.x;
    const int wid = __builtin_amdgcn_readfirstlane(t >> 6);
    const int d = blockIdx.x * 4 + wid;
    if (d >= NN) return;
    const int lane = t & 63;
    const int ch2 = lane << 1;

    const int beg = rowptr[d];
    const int end = rowptr[d + 1];

    float2 qv = __half22float2(*(const __half2*)(q1 + (size_t)d * 128 + ch2));
    qv.x *= 0.17677669529663687f;  // fold 1/sqrt(32) into q
    qv.y *= 0.17677669529663687f;

    float2 accA = make_float2(0.f, 0.f), accB = make_float2(0.f, 0.f);
    float sA = 0.f, sB = 0.f;

    int i = beg;
    int sa = (i < end) ? esrc[i] : 0;
    int sb = (i + 1 < end) ? esrc[i + 1] : 0;
    unsigned kA = *(const unsigned short*)(k8 + (size_t)sa * 128 + ch2);
    unsigned vA = *(const unsigned short*)(v8 + (size_t)sa * 128 + ch2);
    unsigned kB = *(const unsigned short*)(k8 + (size_t)sb * 128 + ch2);
    unsigned vB = *(const unsigned short*)(v8 + (size_t)sb * 128 + ch2);

    while (i + 1 < end) {
        const int ni = i + 2;
        const int nsa = (ni < end) ? esrc[ni] : 0;
        const int nsb = (ni + 1 < end) ? esrc[ni + 1] : 0;
        const unsigned nkA = *(const unsigned short*)(k8 + (size_t)nsa * 128 + ch2);
        const unsigned nvA = *(const unsigned short*)(v8 + (size_t)nsa * 128 + ch2);
        const unsigned nkB = *(const unsigned short*)(k8 + (size_t)nsb * 128 + ch2);
        const unsigned nvB = *(const unsigned short*)(v8 + (size_t)nsb * 128 + ch2);

        const f32x2 kAf = __builtin_amdgcn_cvt_pk_f32_fp8((int)kA, false);
        const f32x2 kBf = __builtin_amdgcn_cvt_pk_f32_fp8((int)kB, false);
        const f32x2 vAf = __builtin_amdgcn_cvt_pk_f32_fp8((int)vA, false);
        const f32x2 vBf = __builtin_amdgcn_cvt_pk_f32_fp8((int)vB, false);

        float pA = qv.x * kAf[0] + qv.y * kAf[1];
        float pB = qv.x * kBf[0] + qv.y * kBf[1];
        pA += __shfl_xor(pA, 8, 16); pB += __shfl_xor(pB, 8, 16);
        pA += __shfl_xor(pA, 4, 16); pB += __shfl_xor(pB, 4, 16);
        pA += __shfl_xor(pA, 2, 16); pB += __shfl_xor(pB, 2, 16);
        pA += __shfl_xor(pA, 1, 16); pB += __shfl_xor(pB, 1, 16);

        const float exA = __expf(pA - 4.0f);
        accA.x += exA * vAf[0];
        accA.y += exA * vAf[1];
        sA += exA;

        const float exB = __expf(pB - 4.0f);
        accB.x += exB * vBf[0];
        accB.y += exB * vBf[1];
        sB += exB;

        kA = nkA; vA = nvA; kB = nkB; vB = nvB;
        i = ni;
    }
    if (i < end) {  // odd tail -> chain A
        const f32x2 kAf = __builtin_amdgcn_cvt_pk_f32_fp8((int)kA, false);
        const f32x2 vAf = __builtin_amdgcn_cvt_pk_f32_fp8((int)vA, false);
        float pA = qv.x * kAf[0] + qv.y * kAf[1];
        pA += __shfl_xor(pA, 8, 16);
        pA += __shfl_xor(pA, 4, 16);
        pA += __shfl_xor(pA, 2, 16);
        pA += __shfl_xor(pA, 1, 16);
        const float exA = __expf(pA - 4.0f);
        accA.x += exA * vAf[0];
        accA.y += exA * vAf[1];
        sA += exA;
    }

    const float inv = 1.f / (sA + sB + 1e-16f);
    float2 o = __half22float2(*(const __half2*)(skiph + (size_t)d * 128 + ch2));
    o.x = elu1(o.x + (accA.x + accB.x) * inv);
    o.y = elu1(o.y + (accA.y + accB.y) * inv);
    *(__half2*)(hb + (size_t)d * 128 + ch2) = __floats2half2_rn(o.x, o.y);
}

// ---------- layer-2 projections via MFMA: h[N,128] @ W2t^T + bias2 ----------
__global__ __launch_bounds__(128) void node_l2_mfma(
    const __half* __restrict__ hb, const __half* __restrict__ W2t,
    const float* __restrict__ bias2,
    __half* __restrict__ q2h, __half* __restrict__ kv2h,
    float* __restrict__ out)
{
    const int t = threadIdx.x;
    const int wave = t >> 6;
    const int lane = t & 63;
    const int l = lane & 15;
    const int g = lane >> 4;  // 0..3
    const int wrow0 = blockIdx.x * 128 + wave * 64;
    if (wrow0 >= NN) return;
    const bool full = (wrow0 + 64 <= NN);

    f16x8 hf[4][4];
    #pragma unroll
    for (int rt = 0; rt < 4; ++rt) {
        int arow = wrow0 + rt * 16 + l;
        if (!full && arow >= NN) arow = NN - 1;
        #pragma unroll
        for (int kk = 0; kk < 4; ++kk)
            hf[rt][kk] = *(const f16x8*)((const _Float16*)hb + (size_t)arow * 128 + kk * 32 + g * 8);
    }

    #pragma unroll
    for (int ct = 0; ct < 4; ++ct) {
        const int col = ct * 16 + l;
        f16x8 wf[4];
        #pragma unroll
        for (int kk = 0; kk < 4; ++kk)
            wf[kk] = *(const f16x8*)((const _Float16*)W2t + (size_t)col * 128 + kk * 32 + g * 8);

        f32x4 acc[4];
        #pragma unroll
        for (int rt = 0; rt < 4; ++rt) acc[rt] = (f32x4){0.f, 0.f, 0.f, 0.f};
        #pragma unroll
        for (int kk = 0; kk < 4; ++kk)
            #pragma unroll
            for (int rt = 0; rt < 4; ++rt)
                acc[rt] = __builtin_amdgcn_mfma_f32_16x16x32_f16(wf[kk], hf[rt][kk], acc[rt], 0, 0, 0);

        const int c0 = g * 4;
        const float4 bias = *(const float4*)(bias2 + ct * 16 + c0);
        #pragma unroll
        for (int rt = 0; rt < 4; ++rt) {
            const int row = wrow0 + rt * 16 + l;
            if (full || row < NN) {
                float4 r;
                r.x = acc[rt][0] + bias.x;
                r.y = acc[rt][1] + bias.y;
                r.z = acc[rt][2] + bias.z;
                r.w = acc[rt][3] + bias.w;
                if (ct == 3) {
                    if (g < 2) {
                        *(float4*)(out + (size_t)row * 10 + c0) = r;
                    } else if (g == 2) {
                        out[(size_t)row * 10 + 8] = r.x;
                        out[(size_t)row * 10 + 9] = r.y;
                    }
                } else {
                    __half* p = ct == 0 ? q2h + (size_t)row * 16 + c0
                              : kv2h + (size_t)row * 32 + (ct == 2 ? 16 : 0) + c0;
                    __half2 h01 = __floats2half2_rn(r.x, r.y);
                    __half2 h23 = __floats2half2_rn(r.z, r.w);
                    uint2 u;
                    u.x = *(unsigned*)&h01;
                    u.y = *(unsigned*)&h23;
                    *(uint2*)p = u;
                }
            }
        }
    }
}

// ---------- layer-2 fused attention: 8 lanes/dst, 4 chains, half2 loads ----------
__global__ __launch_bounds__(256) void node_attn2(
    const __half* __restrict__ q2h, const __half* __restrict__ kv2h,
    const int* __restrict__ rowptr, const int* __restrict__ esrc,
    float* __restrict__ out)  // pre-loaded with skip (h @ Ws2 + bs2)
{
    const int t = threadIdx.x;
    const int d = blockIdx.x * 32 + (t >> 3);
    if (d >= NN) return;
    const int c = t & 7;  // channel pair (2c, 2c+1)
    const int beg = rowptr[d];
    const int end = rowptr[d + 1];

    float2 qv = __half22float2(*(const __half2*)(q2h + (size_t)d * 16 + 2 * c));
    qv.x *= 0.31622776601683794f;  // fold 1/sqrt(10)
    qv.y *= 0.31622776601683794f;

    float2 acc[4];
    float ss[4];
    #pragma unroll
    for (int j = 0; j < 4; ++j) { acc[j] = make_float2(0.f, 0.f); ss[j] = 0.f; }

    int i = beg;
    __half2 kr[4], vr[4];
    #pragma unroll
    for (int j = 0; j < 4; ++j) {
        const int s = (i + j < end) ? esrc[i + j] : 0;
        kr[j] = *(const __half2*)(kv2h + (size_t)s * 32 + 2 * c);
        vr[j] = *(const __half2*)(kv2h + (size_t)s * 32 + 16 + 2 * c);
    }

    while (i + 3 < end) {
        const int ni = i + 4;
        __half2 nk[4], nv[4];
        #pragma unroll
        for (int j = 0; j < 4; ++j) {
            const int s = (ni + j < end) ? esrc[ni + j] : 0;
            nk[j] = *(const __half2*)(kv2h + (size_t)s * 32 + 2 * c);
            nv[j] = *(const __half2*)(kv2h + (size_t)s * 32 + 16 + 2 * c);
        }
        #pragma unroll
        for (int j = 0; j < 4; ++j) {
            const float2 kf = __half22float2(kr[j]);
            const float2 vf = __half22float2(vr[j]);
            float p = qv.x * kf.x + qv.y * kf.y;
            p += __shfl_xor(p, 4, 8);
            p += __shfl_xor(p, 2, 8);
            p += __shfl_xor(p, 1, 8);
            const float ex = __expf(p - 2.0f);
            acc[j].x += ex * vf.x;
            acc[j].y += ex * vf.y;
            ss[j] += ex;
        }
        #pragma unroll
        for (int j = 0; j < 4; ++j) { kr[j] = nk[j]; vr[j] = nv[j]; }
        i = ni;
    }
    for (; i < end; ++i) {
        const int s = esrc[i];
        const float2 kf = __half22float2(*(const __half2*)(kv2h + (size_t)s * 32 + 2 * c));
        const float2 vf = __half22float2(*(const __half2*)(kv2h + (size_t)s * 32 + 16 + 2 * c));
        float p = qv.x * kf.x + qv.y * kf.y;
        p += __shfl_xor(p, 4, 8);
        p += __shfl_xor(p, 2, 8);
        p += __shfl_xor(p, 1, 8);
        const float ex = __expf(p - 2.0f);
        acc[0].x += ex * vf.x;
        acc[0].y += ex * vf.y;
        ss[0] += ex;
    }

    if (c < 5) {
        const float ssum = ss[0] + ss[1] + ss[2] + ss[3];
        const float inv = 1.f / (ssum + 1e-16f);
        float2 o = *(float2*)(out + (size_t)d * 10 + 2 * c);
        o.x += (acc[0].x + acc[1].x + acc[2].x + acc[3].x) * inv;
        o.y += (acc[0].y + acc[1].y + acc[2].y + acc[3].y) * inv;
        *(float2*)(out + (size_t)d * 10 + 2 * c) = o;
    }
}

extern "C" void kernel_launch(void* const* d_in, const int* in_sizes, int n_in,
                              void* d_out, int out_size, void* d_ws, size_t ws_size,
                              hipStream_t stream) {
    const float* x   = (const float*)d_in[0];
    const int*   ei  = (const int*)d_in[1];
    const float* Wq1 = (const float*)d_in[2];  const float* bq1 = (const float*)d_in[3];
    const float* Wk1 = (const float*)d_in[4];  const float* bk1 = (const float*)d_in[5];
    const float* Wv1 = (const float*)d_in[6];  const float* bv1 = (const float*)d_in[7];
    const float* Ws1 = (const float*)d_in[8];  const float* bs1 = (const float*)d_in[9];
    const float* Wq2 = (const float*)d_in[10]; const float* bq2 = (const float*)d_in[11];
    const float* Wk2 = (const float*)d_in[12]; const float* bk2 = (const float*)d_in[13];
    const float* Wv2 = (const float*)d_in[14]; const float* bv2 = (const float*)d_in[15];
    const float* Ws2 = (const float*)d_in[16]; const float* bs2 = (const float*)d_in[17];
    float* out = (float*)d_out;

    const int* src = ei;
    const int* dst = ei + EE;

    // workspace carve
    __half* xh    = (__half*)d_ws;                      // N*128 f16 (x)
    __half* q1h   = xh + (size_t)NN * 128;              // N*128 f16
    __half* skiph = q1h + (size_t)NN * 128;             // N*128 f16 (x @ Ws + bs)
    __half* hb    = skiph + (size_t)NN * 128;           // N*128 f16 (h)
    unsigned char* k8 = (unsigned char*)(hb + (size_t)NN * 128);  // N*128 fp8
    unsigned char* v8 = k8 + (size_t)NN * 128;          // N*128 fp8
    __half* Wt    = (__half*)(v8 + (size_t)NN * 128);   // 4*128*128 f16
    __half* W2t   = Wt + 4 * 128 * 128;                 // 64*128 f16
    __half* q2h   = W2t + 64 * 128;                     // N*16 f16 (padded)
    __half* kv2h  = q2h + (size_t)NN * 16;              // N*32 f16 (k|v packed)
    float* bias2  = (float*)(kv2h + (size_t)NN * 32);   // 64 f32
    int* deg      = (int*)(bias2 + 64);                 // N
    int* rowptr   = deg + NN;                           // N+1
    int* bcur     = rowptr + NN + 1;                    // NBK bucket cursors
    int* bsum     = bcur + NBK;                         // NB
    int* esrc     = bsum + NB;                          // E (src sorted by dst)
    unsigned* bpair = (unsigned*)(esrc + EE);           // E packed (dst<<16)|src

    // prep: streaming x->f16 with hidden histogram; weight repacks
    hipMemsetAsync(deg, 0, (size_t)NN * sizeof(int), stream);
    convert_x_deg<<<(NN * 32 + 255) / 256, 256, 0, stream>>>(x, xh, dst, deg);
    build_weights<<<64, 256, 0, stream>>>(Wq1, Wk1, Wv1, Ws1,
                                          Wq2, bq2, Wk2, bk2, Wv2, bv2, Ws2, bs2,
                                          Wt, W2t, bias2);

    // CSR build: scan -> rowptr+bucket cursors -> two-pass bucketed scatter
    block_sums<<<NB, 256, 0, stream>>>(deg, bsum);
    scan_bsums<<<1, 256, 0, stream>>>(bsum);
    write_rowptr<<<NB, 256, 0, stream>>>(deg, bsum, rowptr, bcur);
    bucket_stage<<<(EE + CH - 1) / CH, 256, 0, stream>>>(src, dst, bcur, bpair);
    bucket_scatter<<<NBK, 256, 0, stream>>>(bpair, rowptr, esrc);

    // layer 1 projections via MFMA (q/skip f16, k/v fp8, LDS-staged stores)
    gemm_l1_mfma<<<dim3((NN + 127) / 128, 2), 128, 0, stream>>>(
        xh, Wt, bq1, bk1, bv1, bs1, q1h, k8, v8, skiph);

    // fused layer-1 attention + skip + ELU -> h fp16 (fp8 k/v gather)
    node_attn1<<<NN / 4, 256, 0, stream>>>(q1h, k8, v8, rowptr, esrc, skiph, hb);

    // layer-2 projections via MFMA (s2 written directly to d_out)
    node_l2_mfma<<<(NN + 127) / 128, 128, 0, stream>>>(hb, W2t, bias2, q2h, kv2h, out);

    // fused layer-2 attention (8 lanes/dst, 4 chains)
    node_attn2<<<(NN + 31) / 32, 256, 0, stream>>>(q2h, kv2h, rowptr, esrc, out);
}

// Round 20
// 186.616 us; speedup vs baseline: 1.2493x; 1.0244x over previous
//
#include <hip/hip_runtime.h>
#include <hip/hip_fp16.h>
#include <math.h>

#define NN 50000
#define EE 800000
#define NB 196   // ceil(NN/256)
#define NBK 128  // dst-range buckets
#define BKN 391  // nodes per bucket (128*391 = 50048 >= NN)
#define CH 4096  // edges per bucket_stage block
// IN_DIM = 128, HEADS*HIDDEN = 128, NUM_CLASSES = 10

typedef _Float16 f16x8 __attribute__((ext_vector_type(8)));
typedef float f32x4 __attribute__((ext_vector_type(4)));
typedef float f32x2 __attribute__((ext_vector_type(2)));

__device__ inline float elu1(float x) { return x > 0.f ? x : expm1f(x); }

// ---------- prep: x (f32) -> xh (f16), dst-degree histogram hidden under the stream ----------
__global__ __launch_bounds__(256) void convert_x_deg(
    const float* __restrict__ x, __half* __restrict__ xh,
    const int* __restrict__ dst, int* __restrict__ deg)
{
    const int i = blockIdx.x * 256 + threadIdx.x;  // float4 index
    if (i < NN * 32) {
        const float4 v = ((const float4*)x)[i];
        ((__half2*)xh)[i * 2] = __floats2half2_rn(v.x, v.y);
        ((__half2*)xh)[i * 2 + 1] = __floats2half2_rn(v.z, v.w);
    }
    if (i < EE) atomicAdd(&deg[dst[i]], 1);
}

// ---------- prep: W1 transpose (f16) + W2 pack (f16, zero-padded) in one kernel ----------
__global__ __launch_bounds__(256) void build_weights(
    const float* __restrict__ Wq, const float* __restrict__ Wk,
    const float* __restrict__ Wv, const float* __restrict__ Ws,
    const float* __restrict__ Wq2, const float* __restrict__ bq2,
    const float* __restrict__ Wk2, const float* __restrict__ bk2,
    const float* __restrict__ Wv2, const float* __restrict__ bv2,
    const float* __restrict__ Ws2, const float* __restrict__ bs2,
    __half* __restrict__ Wt, __half* __restrict__ W2t, float* __restrict__ bias2)
{
    const int idx = blockIdx.x * 256 + threadIdx.x;
    if (idx < 8192) {
        const int col = idx >> 7, k = idx & 127;
        const int m = col >> 4, j = col & 15;
        const float* W = m == 0 ? Wq2 : m == 1 ? Wk2 : m == 2 ? Wv2 : Ws2;
        W2t[idx] = (__half)(j < 10 ? W[k * 10 + j] : 0.f);
    }
    if (idx < 64) {
        const int m = idx >> 4, j = idx & 15;
        const float* b = m == 0 ? bq2 : m == 1 ? bk2 : m == 2 ? bv2 : bs2;
        bias2[idx] = j < 10 ? b[j] : 0.f;
    }
    __shared__ float tile[32][33];
    const int mat = blockIdx.x >> 4;
    const int tid = blockIdx.x & 15;
    const int k0 = (tid >> 2) * 32, c0 = (tid & 3) * 32;
    const float* W = mat == 0 ? Wq : mat == 1 ? Wk : mat == 2 ? Wv : Ws;
    const int r = threadIdx.x >> 5;   // 0..7
    const int c = threadIdx.x & 31;
    for (int rr = r; rr < 32; rr += 8) tile[rr][c] = W[(size_t)(k0 + rr) * 128 + c0 + c];
    __syncthreads();
    for (int rr = r; rr < 32; rr += 8)
        Wt[((size_t)mat * 128 + c0 + rr) * 128 + k0 + c] = (__half)tile[c][rr];
}

// ---------- CSR build: multi-block scan ----------
__global__ __launch_bounds__(256) void block_sums(
    const int* __restrict__ deg, int* __restrict__ bsum)
{
    __shared__ int ws[4];
    const int t = threadIdx.x;
    const int idx = blockIdx.x * 256 + t;
    int d = (idx < NN) ? deg[idx] : 0;
    #pragma unroll
    for (int off = 32; off; off >>= 1) d += __shfl_down(d, off, 64);
    if ((t & 63) == 0) ws[t >> 6] = d;
    __syncthreads();
    if (t == 0) bsum[blockIdx.x] = ws[0] + ws[1] + ws[2] + ws[3];
}

__global__ __launch_bounds__(256) void scan_bsums(int* __restrict__ bsum)
{
    __shared__ int s[256];
    const int t = threadIdx.x;
    int v = (t < NB) ? bsum[t] : 0;
    s[t] = v;
    __syncthreads();
    for (int off = 1; off < 256; off <<= 1) {
        int u = (t >= off) ? s[t - off] : 0;
        __syncthreads();
        s[t] += u;
        __syncthreads();
    }
    if (t < NB) bsum[t] = (t == 0) ? 0 : s[t - 1];
}

// rowptr + bucket cursors (bcur[b] = rowptr[b*BKN], bucket base in esrc/bpair)
__global__ __launch_bounds__(256) void write_rowptr(
    const int* __restrict__ deg, const int* __restrict__ bsum,
    int* __restrict__ rowptr, int* __restrict__ bcur)
{
    __shared__ int s[256];
    const int t = threadIdx.x;
    const int idx = blockIdx.x * 256 + t;
    const int d = (idx < NN) ? deg[idx] : 0;
    s[t] = d;
    __syncthreads();
    for (int off = 1; off < 256; off <<= 1) {
        int u = (t >= off) ? s[t - off] : 0;
        __syncthreads();
        s[t] += u;
        __syncthreads();
    }
    const int excl = ((t == 0) ? 0 : s[t - 1]) + bsum[blockIdx.x];
    if (idx < NN) {
        rowptr[idx] = excl;
        if (idx % BKN == 0) bcur[idx / BKN] = excl;
    }
    if (idx == NN - 1) rowptr[NN] = excl + d;  // == EE
}

// ---------- pass 1: bucket edges by dst range; LDS-sorted chunks, bulk-reserved
// contiguous copy-out -> bpair writes are (near-)full lines.
__global__ __launch_bounds__(256) void bucket_stage(
    const int* __restrict__ src, const int* __restrict__ dst,
    int* __restrict__ bcur, unsigned* __restrict__ bpair)
{
    __shared__ unsigned ep[CH];        // packed (dst<<16)|src
    __shared__ unsigned short eb[CH];  // bucket id
    __shared__ unsigned stg[CH];       // bucket-sorted
    __shared__ int cnt[NBK], off[NBK], pos[NBK], gbase[NBK];
    const int t = threadIdx.x;
    const int e0 = blockIdx.x * CH;
    const int n = min(CH, EE - e0);
    if (t < NBK) cnt[t] = 0;
    __syncthreads();
    for (int i = t; i < n; i += 256) {
        const int s = src[e0 + i], d = dst[e0 + i];
        ep[i] = (unsigned)s | ((unsigned)d << 16);
        const int b = d / BKN;
        eb[i] = (unsigned short)b;
        atomicAdd(&cnt[b], 1);
    }
    __syncthreads();
    if (t == 0) {
        int run = 0;
        for (int b = 0; b < NBK; ++b) { off[b] = run; pos[b] = run; run += cnt[b]; }
    }
    __syncthreads();
    if (t < NBK && cnt[t] > 0) gbase[t] = atomicAdd(&bcur[t], cnt[t]);
    __syncthreads();
    for (int i = t; i < n; i += 256) {
        const int b = eb[i];
        const int p = atomicAdd(&pos[b], 1);
        stg[p] = ep[i];
    }
    __syncthreads();
    for (int i = t; i < n; i += 256) {
        int lo = 0, hi = NBK - 1;
        while (lo < hi) { const int mid = (lo + hi + 1) >> 1; if (off[mid] <= i) lo = mid; else hi = mid - 1; }
        bpair[gbase[lo] + (i - off[lo])] = stg[i];
    }
}

// ---------- pass 2: one block per bucket; LDS cursors; esrc range exclusive ----------
__global__ __launch_bounds__(256) void bucket_scatter(
    const unsigned* __restrict__ bpair, const int* __restrict__ rowptr,
    int* __restrict__ esrc)
{
    __shared__ int lcur[BKN];
    const int b = blockIdx.x;
    const int n0 = b * BKN;
    const int n1 = min(NN, n0 + BKN);
    const int nn = n1 - n0;
    const int t = threadIdx.x;
    for (int i = t; i < nn; i += 256) lcur[i] = rowptr[n0 + i];
    __syncthreads();
    const int ebeg = rowptr[n0];
    const int eend = rowptr[n1];
    for (int i = ebeg + t; i < eend; i += 256) {
        const unsigned p = bpair[i];
        const int s = (int)(p & 0xFFFFu);
        const int d = (int)(p >> 16);
        const int pos = atomicAdd(&lcur[d - n0], 1);
        esrc[pos] = s;
    }
}

// ---------- layer-1 projections via MFMA: 2 mats per block, 64-row waves ----------
// q/skip f16; k/v fp8 e4m3. LDS-staged full-line stores.
__global__ __launch_bounds__(128) void gemm_l1_mfma(
    const __half* __restrict__ xh, const __half* __restrict__ Wt,
    const float* __restrict__ bq, const float* __restrict__ bk,
    const float* __restrict__ bv, const float* __restrict__ bs,
    __half* __restrict__ oqh, unsigned char* __restrict__ ok8,
    unsigned char* __restrict__ ov8, __half* __restrict__ osh)
{
    __shared__ __align__(16) unsigned char ldsraw[128 * 272];  // 34 KB
    const int pair = blockIdx.y;  // 0: mats {0(q f16),1(k fp8)}; 1: mats {2(v fp8),3(s f16)}
    const int t = threadIdx.x;
    const int wave = t >> 6;
    const int lane = t & 63;
    const int l = lane & 15;
    const int g = lane >> 4;  // 0..3
    const int brow0 = blockIdx.x * 128;
    const int wrow0 = brow0 + wave * 64;

    f16x8 xf[4][4];
    #pragma unroll
    for (int rt = 0; rt < 4; ++rt) {
        int arow = wrow0 + rt * 16 + l;
        if (arow >= NN) arow = NN - 1;  // clamp: garbage rows never stored
        #pragma unroll
        for (int kk = 0; kk < 4; ++kk)
            xf[rt][kk] = *(const f16x8*)((const _Float16*)xh + (size_t)arow * 128 + kk * 32 + g * 8);
    }

    for (int mi = 0; mi < 2; ++mi) {
        const int mat = pair * 2 + mi;
        const bool isfp8 = (mat == 1 || mat == 2);
        const float* b = mat == 0 ? bq : mat == 1 ? bk : mat == 2 ? bv : bs;
        const _Float16* wt = (const _Float16*)Wt + (size_t)mat * 128 * 128;

        f16x8 wf[4], wfn[4];
        #pragma unroll
        for (int kk = 0; kk < 4; ++kk)
            wf[kk] = *(const f16x8*)(wt + (size_t)l * 128 + kk * 32 + g * 8);

        for (int ct = 0; ct < 8; ++ct) {
            if (ct < 7) {
                const int ncol = (ct + 1) * 16 + l;
                #pragma unroll
                for (int kk = 0; kk < 4; ++kk)
                    wfn[kk] = *(const f16x8*)(wt + (size_t)ncol * 128 + kk * 32 + g * 8);
            }
            f32x4 acc[4];
            #pragma unroll
            for (int rt = 0; rt < 4; ++rt) acc[rt] = (f32x4){0.f, 0.f, 0.f, 0.f};
            #pragma unroll
            for (int kk = 0; kk < 4; ++kk)
                #pragma unroll
                for (int rt = 0; rt < 4; ++rt)
                    acc[rt] = __builtin_amdgcn_mfma_f32_16x16x32_f16(wf[kk], xf[rt][kk], acc[rt], 0, 0, 0);

            const int col0 = ct * 16 + g * 4;
            const float4 bias = *(const float4*)(b + col0);
            #pragma unroll
            for (int rt = 0; rt < 4; ++rt) {
                const int lrow = wave * 64 + rt * 16 + l;
                const float r0 = acc[rt][0] + bias.x;
                const float r1 = acc[rt][1] + bias.y;
                const float r2 = acc[rt][2] + bias.z;
                const float r3 = acc[rt][3] + bias.w;
                if (isfp8) {
                    int p = __builtin_amdgcn_cvt_pk_fp8_f32(r0, r1, 0, false);
                    p = __builtin_amdgcn_cvt_pk_fp8_f32(r2, r3, p, true);
                    *(int*)&ldsraw[lrow * 144 + col0] = p;       // 144B row stride
                } else {
                    __half2 h01 = __floats2half2_rn(r0, r1);
                    __half2 h23 = __floats2half2_rn(r2, r3);
                    uint2 u;
                    u.x = *(unsigned*)&h01;
                    u.y = *(unsigned*)&h23;
                    *(uint2*)&ldsraw[lrow * 272 + col0 * 2] = u; // 272B row stride
                }
            }
            #pragma unroll
            for (int kk = 0; kk < 4; ++kk) wf[kk] = wfn[kk];
        }

        __syncthreads();
        if (isfp8) {
            unsigned char* o = (mat == 1) ? ok8 : ov8;
            #pragma unroll
            for (int i = 0; i < 8; ++i) {
                const int idx = i * 128 + t;
                const int row = idx >> 3;
                const int seg = idx & 7;
                const int grow = brow0 + row;
                if (grow < NN)
                    *(uint4*)(o + (size_t)grow * 128 + seg * 16) = *(const uint4*)&ldsraw[row * 144 + seg * 16];
            }
        } else {
            __half* o = (mat == 0) ? oqh : osh;
            #pragma unroll
            for (int i = 0; i < 16; ++i) {
                const int idx = i * 128 + t;
                const int row = idx >> 4;
                const int seg = idx & 15;
                const int grow = brow0 + row;
                if (grow < NN)
                    *(uint4*)(o + (size_t)grow * 128 + seg * 8) = *(const uint4*)&ldsraw[row * 272 + seg * 16];
            }
        }
        __syncthreads();
    }
}

// ---------- layer-1 fused attention + skip + ELU -> h (fp16) ----------
// 32 lanes/dst x 4 fp8 channels/lane (one u32 load per operand): halves per-edge
// instruction count vs the 64-lane/2-ch version (VALU was 60% busy at R19).
// Head = 8 lanes -> 3-shfl reduce. A/B dual chains for MLP. Static-shift softmax.
__global__ __launch_bounds__(256) void node_attn1(
    const __half* __restrict__ q1, const unsigned char* __restrict__ k8,
    const unsigned char* __restrict__ v8,
    const int* __restrict__ rowptr, const int* __restrict__ esrc,
    const __half* __restrict__ skiph,  // x @ Ws + bs (f16)
    __half* __restrict__ hb)           // out: h = elu(skip + attn), fp16
{
    const int t = threadIdx.x;
    const int d = blockIdx.x * 8 + (t >> 5);
    if (d >= NN) return;
    const int ch4 = (t & 31) << 2;  // channel base (4 channels/lane); head = 8-lane group

    const int beg = rowptr[d];
    const int end = rowptr[d + 1];

    // q: 4 fp16 channels -> 4 floats, pre-scaled
    float q0, q1v, q2, q3;
    {
        const __half2 qa = *(const __half2*)(q1 + (size_t)d * 128 + ch4);
        const __half2 qb = *(const __half2*)(q1 + (size_t)d * 128 + ch4 + 2);
        const float2 fa = __half22float2(qa);
        const float2 fb = __half22float2(qb);
        q0 = fa.x * 0.17677669529663687f;
        q1v = fa.y * 0.17677669529663687f;
        q2 = fb.x * 0.17677669529663687f;
        q3 = fb.y * 0.17677669529663687f;
    }

    f32x4 accA = {0.f, 0.f, 0.f, 0.f}, accB = {0.f, 0.f, 0.f, 0.f};
    float sA = 0.f, sB = 0.f;

    int i = beg;
    int sa = (i < end) ? esrc[i] : 0;
    int sb = (i + 1 < end) ? esrc[i + 1] : 0;
    unsigned kA = *(const unsigned*)(k8 + (size_t)sa * 128 + ch4);
    unsigned vA = *(const unsigned*)(v8 + (size_t)sa * 128 + ch4);
    unsigned kB = *(const unsigned*)(k8 + (size_t)sb * 128 + ch4);
    unsigned vB = *(const unsigned*)(v8 + (size_t)sb * 128 + ch4);

    while (i + 1 < end) {
        const int ni = i + 2;
        const int nsa = (ni < end) ? esrc[ni] : 0;
        const int nsb = (ni + 1 < end) ? esrc[ni + 1] : 0;
        const unsigned nkA = *(const unsigned*)(k8 + (size_t)nsa * 128 + ch4);
        const unsigned nvA = *(const unsigned*)(v8 + (size_t)nsa * 128 + ch4);
        const unsigned nkB = *(const unsigned*)(k8 + (size_t)nsb * 128 + ch4);
        const unsigned nvB = *(const unsigned*)(v8 + (size_t)nsb * 128 + ch4);

        const f32x2 kA01 = __builtin_amdgcn_cvt_pk_f32_fp8((int)kA, false);
        const f32x2 kA23 = __builtin_amdgcn_cvt_pk_f32_fp8((int)kA, true);
        const f32x2 kB01 = __builtin_amdgcn_cvt_pk_f32_fp8((int)kB, false);
        const f32x2 kB23 = __builtin_amdgcn_cvt_pk_f32_fp8((int)kB, true);

        float pA = q0 * kA01[0] + q1v * kA01[1] + q2 * kA23[0] + q3 * kA23[1];
        float pB = q0 * kB01[0] + q1v * kB01[1] + q2 * kB23[0] + q3 * kB23[1];
        pA += __shfl_xor(pA, 4, 8); pB += __shfl_xor(pB, 4, 8);
        pA += __shfl_xor(pA, 2, 8); pB += __shfl_xor(pB, 2, 8);
        pA += __shfl_xor(pA, 1, 8); pB += __shfl_xor(pB, 1, 8);

        const f32x2 vA01 = __builtin_amdgcn_cvt_pk_f32_fp8((int)vA, false);
        const f32x2 vA23 = __builtin_amdgcn_cvt_pk_f32_fp8((int)vA, true);
        const f32x2 vB01 = __builtin_amdgcn_cvt_pk_f32_fp8((int)vB, false);
        const f32x2 vB23 = __builtin_amdgcn_cvt_pk_f32_fp8((int)vB, true);

        const float exA = __expf(pA - 4.0f);
        accA[0] += exA * vA01[0];
        accA[1] += exA * vA01[1];
        accA[2] += exA * vA23[0];
        accA[3] += exA * vA23[1];
        sA += exA;

        const float exB = __expf(pB - 4.0f);
        accB[0] += exB * vB01[0];
        accB[1] += exB * vB01[1];
        accB[2] += exB * vB23[0];
        accB[3] += exB * vB23[1];
        sB += exB;

        kA = nkA; vA = nvA; kB = nkB; vB = nvB;
        i = ni;
    }
    if (i < end) {  // odd tail -> chain A
        const f32x2 kA01 = __builtin_amdgcn_cvt_pk_f32_fp8((int)kA, false);
        const f32x2 kA23 = __builtin_amdgcn_cvt_pk_f32_fp8((int)kA, true);
        float pA = q0 * kA01[0] + q1v * kA01[1] + q2 * kA23[0] + q3 * kA23[1];
        pA += __shfl_xor(pA, 4, 8);
        pA += __shfl_xor(pA, 2, 8);
        pA += __shfl_xor(pA, 1, 8);
        const f32x2 vA01 = __builtin_amdgcn_cvt_pk_f32_fp8((int)vA, false);
        const f32x2 vA23 = __builtin_amdgcn_cvt_pk_f32_fp8((int)vA, true);
        const float exA = __expf(pA - 4.0f);
        accA[0] += exA * vA01[0];
        accA[1] += exA * vA01[1];
        accA[2] += exA * vA23[0];
        accA[3] += exA * vA23[1];
        sA += exA;
    }

    const float inv = 1.f / (sA + sB + 1e-16f);
    const __half2 sk01 = *(const __half2*)(skiph + (size_t)d * 128 + ch4);
    const __half2 sk23 = *(const __half2*)(skiph + (size_t)d * 128 + ch4 + 2);
    const float2 s01 = __half22float2(sk01);
    const float2 s23 = __half22float2(sk23);
    const float o0 = elu1(s01.x + (accA[0] + accB[0]) * inv);
    const float o1 = elu1(s01.y + (accA[1] + accB[1]) * inv);
    const float o2 = elu1(s23.x + (accA[2] + accB[2]) * inv);
    const float o3 = elu1(s23.y + (accA[3] + accB[3]) * inv);
    __half2 h01 = __floats2half2_rn(o0, o1);
    __half2 h23 = __floats2half2_rn(o2, o3);
    uint2 u;
    u.x = *(unsigned*)&h01;
    u.y = *(unsigned*)&h23;
    *(uint2*)(hb + (size_t)d * 128 + ch4) = u;
}

// ---------- layer-2 projections via MFMA: h[N,128] @ W2t^T + bias2 ----------
__global__ __launch_bounds__(128) void node_l2_mfma(
    const __half* __restrict__ hb, const __half* __restrict__ W2t,
    const float* __restrict__ bias2,
    __half* __restrict__ q2h, __half* __restrict__ kv2h,
    float* __restrict__ out)
{
    const int t = threadIdx.x;
    const int wave = t >> 6;
    const int lane = t & 63;
    const int l = lane & 15;
    const int g = lane >> 4;  // 0..3
    const int wrow0 = blockIdx.x * 128 + wave * 64;
    if (wrow0 >= NN) return;
    const bool full = (wrow0 + 64 <= NN);

    f16x8 hf[4][4];
    #pragma unroll
    for (int rt = 0; rt < 4; ++rt) {
        int arow = wrow0 + rt * 16 + l;
        if (!full && arow >= NN) arow = NN - 1;
        #pragma unroll
        for (int kk = 0; kk < 4; ++kk)
            hf[rt][kk] = *(const f16x8*)((const _Float16*)hb + (size_t)arow * 128 + kk * 32 + g * 8);
    }

    #pragma unroll
    for (int ct = 0; ct < 4; ++ct) {
        const int col = ct * 16 + l;
        f16x8 wf[4];
        #pragma unroll
        for (int kk = 0; kk < 4; ++kk)
            wf[kk] = *(const f16x8*)((const _Float16*)W2t + (size_t)col * 128 + kk * 32 + g * 8);

        f32x4 acc[4];
        #pragma unroll
        for (int rt = 0; rt < 4; ++rt) acc[rt] = (f32x4){0.f, 0.f, 0.f, 0.f};
        #pragma unroll
        for (int kk = 0; kk < 4; ++kk)
            #pragma unroll
            for (int rt = 0; rt < 4; ++rt)
                acc[rt] = __builtin_amdgcn_mfma_f32_16x16x32_f16(wf[kk], hf[rt][kk], acc[rt], 0, 0, 0);

        const int c0 = g * 4;
        const float4 bias = *(const float4*)(bias2 + ct * 16 + c0);
        #pragma unroll
        for (int rt = 0; rt < 4; ++rt) {
            const int row = wrow0 + rt * 16 + l;
            if (full || row < NN) {
                float4 r;
                r.x = acc[rt][0] + bias.x;
                r.y = acc[rt][1] + bias.y;
                r.z = acc[rt][2] + bias.z;
                r.w = acc[rt][3] + bias.w;
                if (ct == 3) {
                    if (g < 2) {
                        *(float4*)(out + (size_t)row * 10 + c0) = r;
                    } else if (g == 2) {
                        out[(size_t)row * 10 + 8] = r.x;
                        out[(size_t)row * 10 + 9] = r.y;
                    }
                } else {
                    __half* p = ct == 0 ? q2h + (size_t)row * 16 + c0
                              : kv2h + (size_t)row * 32 + (ct == 2 ? 16 : 0) + c0;
                    __half2 h01 = __floats2half2_rn(r.x, r.y);
                    __half2 h23 = __floats2half2_rn(r.z, r.w);
                    uint2 u;
                    u.x = *(unsigned*)&h01;
                    u.y = *(unsigned*)&h23;
                    *(uint2*)p = u;
                }
            }
        }
    }
}

// ---------- layer-2 fused attention: 8 lanes/dst, 4 chains, half2 loads ----------
__global__ __launch_bounds__(256) void node_attn2(
    const __half* __restrict__ q2h, const __half* __restrict__ kv2h,
    const int* __restrict__ rowptr, const int* __restrict__ esrc,
    float* __restrict__ out)  // pre-loaded with skip (h @ Ws2 + bs2)
{
    const int t = threadIdx.x;
    const int d = blockIdx.x * 32 + (t >> 3);
    if (d >= NN) return;
    const int c = t & 7;  // channel pair (2c, 2c+1)
    const int beg = rowptr[d];
    const int end = rowptr[d + 1];

    float2 qv = __half22float2(*(const __half2*)(q2h + (size_t)d * 16 + 2 * c));
    qv.x *= 0.31622776601683794f;  // fold 1/sqrt(10)
    qv.y *= 0.31622776601683794f;

    float2 acc[4];
    float ss[4];
    #pragma unroll
    for (int j = 0; j < 4; ++j) { acc[j] = make_float2(0.f, 0.f); ss[j] = 0.f; }

    int i = beg;
    __half2 kr[4], vr[4];
    #pragma unroll
    for (int j = 0; j < 4; ++j) {
        const int s = (i + j < end) ? esrc[i + j] : 0;
        kr[j] = *(const __half2*)(kv2h + (size_t)s * 32 + 2 * c);
        vr[j] = *(const __half2*)(kv2h + (size_t)s * 32 + 16 + 2 * c);
    }

    while (i + 3 < end) {
        const int ni = i + 4;
        __half2 nk[4], nv[4];
        #pragma unroll
        for (int j = 0; j < 4; ++j) {
            const int s = (ni + j < end) ? esrc[ni + j] : 0;
            nk[j] = *(const __half2*)(kv2h + (size_t)s * 32 + 2 * c);
            nv[j] = *(const __half2*)(kv2h + (size_t)s * 32 + 16 + 2 * c);
        }
        #pragma unroll
        for (int j = 0; j < 4; ++j) {
            const float2 kf = __half22float2(kr[j]);
            const float2 vf = __half22float2(vr[j]);
            float p = qv.x * kf.x + qv.y * kf.y;
            p += __shfl_xor(p, 4, 8);
            p += __shfl_xor(p, 2, 8);
            p += __shfl_xor(p, 1, 8);
            const float ex = __expf(p - 2.0f);
            acc[j].x += ex * vf.x;
            acc[j].y += ex * vf.y;
            ss[j] += ex;
        }
        #pragma unroll
        for (int j = 0; j < 4; ++j) { kr[j] = nk[j]; vr[j] = nv[j]; }
        i = ni;
    }
    for (; i < end; ++i) {
        const int s = esrc[i];
        const float2 kf = __half22float2(*(const __half2*)(kv2h + (size_t)s * 32 + 2 * c));
        const float2 vf = __half22float2(*(const __half2*)(kv2h + (size_t)s * 32 + 16 + 2 * c));
        float p = qv.x * kf.x + qv.y * kf.y;
        p += __shfl_xor(p, 4, 8);
        p += __shfl_xor(p, 2, 8);
        p += __shfl_xor(p, 1, 8);
        const float ex = __expf(p - 2.0f);
        acc[0].x += ex * vf.x;
        acc[0].y += ex * vf.y;
        ss[0] += ex;
    }

    if (c < 5) {
        const float ssum = ss[0] + ss[1] + ss[2] + ss[3];
        const float inv = 1.f / (ssum + 1e-16f);
        float2 o = *(float2*)(out + (size_t)d * 10 + 2 * c);
        o.x += (acc[0].x + acc[1].x + acc[2].x + acc[3].x) * inv;
        o.y += (acc[0].y + acc[1].y + acc[2].y + acc[3].y) * inv;
        *(float2*)(out + (size_t)d * 10 + 2 * c) = o;
    }
}

extern "C" void kernel_launch(void* const* d_in, const int* in_sizes, int n_in,
                              void* d_out, int out_size, void* d_ws, size_t ws_size,
                              hipStream_t stream) {
    const float* x   = (const float*)d_in[0];
    const int*   ei  = (const int*)d_in[1];
    const float* Wq1 = (const float*)d_in[2];  const float* bq1 = (const float*)d_in[3];
    const float* Wk1 = (const float*)d_in[4];  const float* bk1 = (const float*)d_in[5];
    const float* Wv1 = (const float*)d_in[6];  const float* bv1 = (const float*)d_in[7];
    const float* Ws1 = (const float*)d_in[8];  const float* bs1 = (const float*)d_in[9];
    const float* Wq2 = (const float*)d_in[10]; const float* bq2 = (const float*)d_in[11];
    const float* Wk2 = (const float*)d_in[12]; const float* bk2 = (const float*)d_in[13];
    const float* Wv2 = (const float*)d_in[14]; const float* bv2 = (const float*)d_in[15];
    const float* Ws2 = (const float*)d_in[16]; const float* bs2 = (const float*)d_in[17];
    float* out = (float*)d_out;

    const int* src = ei;
    const int* dst = ei + EE;

    // workspace carve
    __half* xh    = (__half*)d_ws;                      // N*128 f16 (x)
    __half* q1h   = xh + (size_t)NN * 128;              // N*128 f16
    __half* skiph = q1h + (size_t)NN * 128;             // N*128 f16 (x @ Ws + bs)
    __half* hb    = skiph + (size_t)NN * 128;           // N*128 f16 (h)
    unsigned char* k8 = (unsigned char*)(hb + (size_t)NN * 128);  // N*128 fp8
    unsigned char* v8 = k8 + (size_t)NN * 128;          // N*128 fp8
    __half* Wt    = (__half*)(v8 + (size_t)NN * 128);   // 4*128*128 f16
    __half* W2t   = Wt + 4 * 128 * 128;                 // 64*128 f16
    __half* q2h   = W2t + 64 * 128;                     // N*16 f16 (padded)
    __half* kv2h  = q2h + (size_t)NN * 16;              // N*32 f16 (k|v packed)
    float* bias2  = (float*)(kv2h + (size_t)NN * 32);   // 64 f32
    int* deg      = (int*)(bias2 + 64);                 // N
    int* rowptr   = deg + NN;                           // N+1
    int* bcur     = rowptr + NN + 1;                    // NBK bucket cursors
    int* bsum     = bcur + NBK;                         // NB
    int* esrc     = bsum + NB;                          // E (src sorted by dst)
    unsigned* bpair = (unsigned*)(esrc + EE);           // E packed (dst<<16)|src

    // prep: streaming x->f16 with hidden histogram; weight repacks
    hipMemsetAsync(deg, 0, (size_t)NN * sizeof(int), stream);
    convert_x_deg<<<(NN * 32 + 255) / 256, 256, 0, stream>>>(x, xh, dst, deg);
    build_weights<<<64, 256, 0, stream>>>(Wq1, Wk1, Wv1, Ws1,
                                          Wq2, bq2, Wk2, bk2, Wv2, bv2, Ws2, bs2,
                                          Wt, W2t, bias2);

    // CSR build: scan -> rowptr+bucket cursors -> two-pass bucketed scatter
    block_sums<<<NB, 256, 0, stream>>>(deg, bsum);
    scan_bsums<<<1, 256, 0, stream>>>(bsum);
    write_rowptr<<<NB, 256, 0, stream>>>(deg, bsum, rowptr, bcur);
    bucket_stage<<<(EE + CH - 1) / CH, 256, 0, stream>>>(src, dst, bcur, bpair);
    bucket_scatter<<<NBK, 256, 0, stream>>>(bpair, rowptr, esrc);

    // layer 1 projections via MFMA (q/skip f16, k/v fp8, LDS-staged stores)
    gemm_l1_mfma<<<dim3((NN + 127) / 128, 2), 128, 0, stream>>>(
        xh, Wt, bq1, bk1, bv1, bs1, q1h, k8, v8, skiph);

    // fused layer-1 attention + skip + ELU -> h fp16 (32 lanes/dst, u32 fp8 loads)
    node_attn1<<<(NN + 7) / 8, 256, 0, stream>>>(q1h, k8, v8, rowptr, esrc, skiph, hb);

    // layer-2 projections via MFMA (s2 written directly to d_out)
    node_l2_mfma<<<(NN + 127) / 128, 128, 0, stream>>>(hb, W2t, bias2, q2h, kv2h, out);

    // fused layer-2 attention (8 lanes/dst, 4 chains)
    node_attn2<<<(NN + 31) / 32, 256, 0, stream>>>(q2h, kv2h, rowptr, esrc, out);
}